// Round 9
// baseline (169.611 us; speedup 1.0000x reference)
//
#include <hip/hip_runtime.h>

// Problem constants: B=4, C=256, H=W=64, KS=3, N=9
#define HW    4096
#define J_TOT 16384   // B*H*W
#define K_TOT 2304    // 9*256
#define C_CH  256

typedef unsigned short u16;
typedef unsigned int   u32;
typedef __attribute__((ext_vector_type(8))) short short8;   // 8 bf16 (4 VGPRs), MFMA A/B frag
typedef __attribute__((ext_vector_type(4))) float f32x4;    // MFMA C/D frag
typedef __attribute__((ext_vector_type(4))) unsigned short us4;

__device__ __forceinline__ float b2f(u16 u) { return __uint_as_float(((u32)u) << 16); }
__device__ __forceinline__ u16 f2b(float x) {             // RNE f32->bf16
  u32 u = __float_as_uint(x);
  u += 0x7FFFu + ((u >> 16) & 1u);
  return (u16)(u >> 16);
}

// ---------------------------------------------------------------------------
// Kernel 0: dtype detection (1 = bf16 inputs, 0 = f32 inputs).
// ---------------------------------------------------------------------------
__global__ void k_detect(const u16* __restrict__ f, int* __restrict__ flag) {
  __shared__ int sh[256];
  int t = threadIdx.x;
  int hits = 0;
  for (int i = t; i < 2048; i += 256) {
    u16 u = f[2 * i];
    int e = (u >> 7) & 0xFF;
    hits += (e >= 100 && e <= 141) ? 1 : 0;
  }
  sh[t] = hits;
  __syncthreads();
  if (t == 0) {
    int s = 0;
    for (int i = 0; i < 256; i++) s += sh[i];
    flag[0] = (s > 1024) ? 1 : 0;
  }
}

// ---------------------------------------------------------------------------
// Kernel 1 (merged prep): z<4 -> feature (b,c,h,w) -> channels-last bf16
// ftr[b][hw][c] (b = blockIdx.z); z==4 -> weight (o,c,3,3) -> Wr[o][k],
// k = n*256+c.
// ---------------------------------------------------------------------------
__global__ void k_prep(const void* __restrict__ featv, u16* __restrict__ ftr,
                       const void* __restrict__ wv, u16* __restrict__ Wr,
                       const int* __restrict__ flag) {
  int isbf = *flag;
  int tx = threadIdx.x;  // 0..31
  int ty = threadIdx.y;  // 0..7
  int z = blockIdx.z;
  if (z < 4) {
    __shared__ u16 tile[32][33];
    int b = z;
    int hw0 = blockIdx.x << 5;
    int c0 = blockIdx.y << 5;
    if (isbf) {
      const u16* f = (const u16*)featv;
#pragma unroll
      for (int i = 0; i < 4; i++) {
        int c = c0 + ty + i * 8;
        tile[ty + i * 8][tx] = f[(((size_t)(b * C_CH + c)) << 12) + hw0 + tx];
      }
    } else {
      const float* f = (const float*)featv;
#pragma unroll
      for (int i = 0; i < 4; i++) {
        int c = c0 + ty + i * 8;
        tile[ty + i * 8][tx] = f2b(f[(((size_t)(b * C_CH + c)) << 12) + hw0 + tx]);
      }
    }
    __syncthreads();
#pragma unroll
    for (int i = 0; i < 4; i++) {
      int hw = hw0 + ty + i * 8;
      ftr[(((size_t)(b * HW + hw)) << 8) + c0 + tx] = tile[tx][ty + i * 8];
    }
  } else {
    // weight repack: grid-stride over 589824 elems
    int bid = blockIdx.x + (blockIdx.y << 7);
    int flat = ty * 32 + tx;
    for (int idx = bid * 256 + flat; idx < C_CH * K_TOT; idx += 1024 * 256) {
      int c = idx & 255;
      int n = (idx >> 8) % 9;
      int o = idx / K_TOT;
      int src = (o * 256 + c) * 9 + n;
      if (isbf) Wr[idx] = ((const u16*)wv)[src];
      else      Wr[idx] = f2b(((const float*)wv)[src]);
    }
  }
}

// ---------------------------------------------------------------------------
// Kernel 2 (FUSED gather+GEMM): r8 structure + ONE delta: A (Wr) fragments
// load DIRECTLY global->VGPR (two-slot depth-1 prefetch, consumed a full
// ~3700-cyc iteration after issue -- unlike r7's 300-cyc sub-iter, which is
// why r7 stalled). Algebra verified on HW in r7: direct load of Wr row
// (wo*32+oi*16+lr), col tile*64+kk*32+lk*8 is bit-identical to the swizzled
// LDS path (swz=lr&7=row&7 cancels). Deletes A-DMA + A LDS writes + 4 of 8
// frag reads/wave: LDS pipe ~1900 -> ~870 cyc/iter (was 51%, the r8
// ledger's top consumer). No LDS-DMA left -> barrier is lgkmcnt(0) only;
// VMEM never force-drained (compiler tracks reg-load deps).
//
// Block = 64j x 256o, 1024 thr = 16 waves (2j x 8o), wave tile 32jx32o,
// grid 256 = 1 block/CU = 4 waves/SIMD. XCD-chunked swizzle (r8: FETCH 3x
// cut, kept). B produced in LDS by bilinear interp (dup-1), triple-buffered;
// np-cadenced table cache; swizzle slot cg^(p&7), reader g^(row&7)
// (0 conflicts measured). LDS 42KB: Bs 3x8KB + tables 18KB.
// ---------------------------------------------------------------------------
#define NT 36   // K_TOT / 64

#define MFMA_ __builtin_amdgcn_mfma_f32_16x16x32_bf16

// A-fragment prefetch for `tile` into reg slot P (P##00=oi0kk0, P##01=oi0kk1,
// P##10=oi1kk0, P##11=oi1kk1)
#define ALOAD(tile, P)                                                       \
  do {                                                                       \
    const u16* ab_ = Wr + awoff + (tile) * 64;                               \
    P##00 = *(const short8*)(ab_);                                           \
    P##01 = *(const short8*)(ab_ + 32);                                      \
    P##10 = *(const short8*)(ab_ + 16 * K_TOT);                              \
    P##11 = *(const short8*)(ab_ + 16 * K_TOT + 32);                         \
  } while (0)

// load corner q-regs + snapshot weights for `tile` into slot P (a or b)
#define PLOAD_S(tile, P)                                                     \
  do {                                                                       \
    if (((tile) & 3) == 0) {                                                 \
      int np_ = (tile) >> 2;                                                 \
      tw0 = gs[np_][0][pp]; tw1 = gs[np_][1][pp];                            \
      tw2 = gs[np_][2][pp]; tw3 = gs[np_][3][pp];                            \
      ti0 = isx[np_][0][pp]; ti1 = isx[np_][1][pp];                          \
      ti2 = isx[np_][2][pp]; ti3 = isx[np_][3][pp];                          \
    }                                                                        \
    int c0_ = (((tile) & 3) << 6) + cb4;                                     \
    P##w0 = tw0; P##w1 = tw1; P##w2 = tw2; P##w3 = tw3;                      \
    P##q0 = *(const us4*)(ftr + ti0 + c0_);                                  \
    P##q1 = *(const us4*)(ftr + ti1 + c0_);                                  \
    P##q2 = *(const us4*)(ftr + ti2 + c0_);                                  \
    P##q3 = *(const us4*)(ftr + ti3 + c0_);                                  \
  } while (0)

#define PFIN_S(P, Bb)                                                        \
  do {                                                                       \
    us4 ov;                                                                  \
    _Pragma("unroll")                                                        \
    for (int i = 0; i < 4; i++) {                                            \
      float v = P##w0 * b2f(P##q0[i]) + P##w1 * b2f(P##q1[i]) +              \
                P##w2 * b2f(P##q2[i]) + P##w3 * b2f(P##q3[i]);               \
      ov[i] = f2b(v);                                                        \
    }                                                                        \
    *(us4*)((Bb) + bofs) = ov;                                               \
  } while (0)

// compute one K=64 tile: A regs in slot P, B tile in LDS buffer Bb
#define GEMM_COMPUTE(P, Bb)                                                  \
  do {                                                                       \
    int go0 = (lk ^ swz) << 3;                                               \
    int go1 = ((4 + lk) ^ swz) << 3;                                         \
    short8 b00 = *(const short8*)((Bb) + (wj * 32 + lr) * 64 + go0);         \
    short8 b10 = *(const short8*)((Bb) + (wj * 32 + 16 + lr) * 64 + go0);    \
    short8 b01 = *(const short8*)((Bb) + (wj * 32 + lr) * 64 + go1);         \
    short8 b11 = *(const short8*)((Bb) + (wj * 32 + 16 + lr) * 64 + go1);    \
    __builtin_amdgcn_s_setprio(1);                                           \
    acc[0][0] = MFMA_(P##00, b00, acc[0][0], 0, 0, 0);                       \
    acc[0][1] = MFMA_(P##00, b10, acc[0][1], 0, 0, 0);                       \
    acc[1][0] = MFMA_(P##10, b00, acc[1][0], 0, 0, 0);                       \
    acc[1][1] = MFMA_(P##10, b10, acc[1][1], 0, 0, 0);                       \
    acc[0][0] = MFMA_(P##01, b01, acc[0][0], 0, 0, 0);                       \
    acc[0][1] = MFMA_(P##01, b11, acc[0][1], 0, 0, 0);                       \
    acc[1][0] = MFMA_(P##11, b01, acc[1][0], 0, 0, 0);                       \
    acc[1][1] = MFMA_(P##11, b11, acc[1][1], 0, 0, 0);                       \
    __builtin_amdgcn_s_setprio(0);                                           \
  } while (0)

#define CBAR()                                                               \
  do {                                                                       \
    asm volatile("s_waitcnt lgkmcnt(0)" ::: "memory");                       \
    __builtin_amdgcn_s_barrier();                                            \
  } while (0)

#define ROTATE()                                                             \
  do {                                                                       \
    u16* tp_ = Bc; Bc = Bn; Bn = Bf; Bf = tp_;                               \
  } while (0)

__global__ __launch_bounds__(1024, 4) void k_gemm(const u16* __restrict__ Wr,
                                                  const u16* __restrict__ ftr,
                                                  const void* __restrict__ offv,
                                                  const void* __restrict__ featv,
                                                  void* __restrict__ outv,
                                                  const int* __restrict__ flag) {
  __shared__ u16 Bs[3][64 * 64];    // [j_row][k] 8KB x3
  __shared__ float gs[9][4][64];    // bilinear weights, 9KB
  __shared__ int   isx[9][4][64];   // corner base offsets (elem, row<<8), 9KB
  int isbf = *flag;
  // XCD-chunked bijective swizzle (nwg=256, 32 consecutive-j blocks per XCD)
  int bid = blockIdx.x;
  int xb = (bid & 7) * 32 + (bid >> 3);
  int j0 = xb << 6;
  int b = j0 >> 12;
  int hw0 = j0 & (HW - 1);
  int t = threadIdx.x;
  int wave = t >> 6, lane = t & 63;
  int wj = wave >> 3, wo = wave & 7;    // 2j x 8o wave grid
  int lr = lane & 15, lk = lane >> 4;
  int swz = lr & 7;

  // ---- phase 0: corner indices + weights for 64 pixels x 9 n (verified) ----
  if (t < 576) {
    int n = t >> 6, p = t & 63;
    int hw = hw0 + p;
    int h = hw >> 6, w = hw & 63;
    size_t obi = (((size_t)(b * 18 + n)) << 12) + hw;
    float ox, oy;
    if (isbf) {
      const u16* po = (const u16*)offv;
      ox = b2f(po[obi]);
      oy = b2f(po[obi + (9u << 12)]);
    } else {
      const float* po = (const float*)offv;
      ox = po[obi];
      oy = po[obi + (9u << 12)];
    }
    int ki = n / 3, kj = n % 3;
    float px = (float)(h + ki) + ox;
    float py = (float)(w + kj) + oy;
    float fx = floorf(px), fy = floorf(py);
    float qltx = fminf(fmaxf(fx, 0.f), 65.f);
    float qlty = fminf(fmaxf(fy, 0.f), 65.f);
    float qrbx = fminf(fmaxf(fx + 1.f, 0.f), 65.f);
    float qrby = fminf(fmaxf(fy + 1.f, 0.f), 65.f);
    float pcx = fminf(fmaxf(px, 0.f), 65.f);
    float pcy = fminf(fmaxf(py, 0.f), 65.f);
    float dltx = 1.f + (qltx - pcx);
    float drbx = 1.f - (qrbx - pcx);
    float dlty = 1.f + (qlty - pcy);
    float drby = 1.f - (qrby - pcy);
    float g0 = dltx * dlty;   // (q_lt_x, q_lt_y)
    float g1 = drbx * drby;   // (q_rb_x, q_rb_y)
    float g2 = dltx * drby;   // (q_lt_x, q_rb_y)
    float g3 = drbx * dlty;   // (q_rb_x, q_lt_y)
    int x0 = (int)qltx, y0 = (int)qlty, x1 = (int)qrbx, y1 = (int)qrby;
    int v0 = (x0 >= 1 && x0 <= 64 && y0 >= 1 && y0 <= 64);
    int v1 = (x1 >= 1 && x1 <= 64 && y1 >= 1 && y1 <= 64);
    int v2 = (x0 >= 1 && x0 <= 64 && y1 >= 1 && y1 <= 64);
    int v3 = (x1 >= 1 && x1 <= 64 && y0 >= 1 && y0 <= 64);
    int base = b << 12;
    isx[n][0][p] = v0 ? ((base + ((x0 - 1) << 6) + (y0 - 1)) << 8) : 0;
    isx[n][1][p] = v1 ? ((base + ((x1 - 1) << 6) + (y1 - 1)) << 8) : 0;
    isx[n][2][p] = v2 ? ((base + ((x0 - 1) << 6) + (y1 - 1)) << 8) : 0;
    isx[n][3][p] = v3 ? ((base + ((x1 - 1) << 6) + (y0 - 1)) << 8) : 0;
    gs[n][0][p] = v0 ? g0 : 0.f;
    gs[n][1][p] = v1 ? g1 : 0.f;
    gs[n][2][p] = v2 ? g2 : 0.f;
    gs[n][3][p] = v3 ? g3 : 0.f;
  }

  f32x4 acc[2][2];   // [oi][ji]
  f32x4 zero = {0.f, 0.f, 0.f, 0.f};
#pragma unroll
  for (int i = 0; i < 2; i++)
#pragma unroll
    for (int j = 0; j < 2; j++) acc[i][j] = zero;

  // A-direct addressing: lane (lr,lk) of wave wo reads Wr rows wo*32+oi*16+lr,
  // k = tile*64 + kk*32 + lk*8 (16B-aligned; 16 rows x 64B per instr).
  const size_t awoff = (size_t)(wo * 32 + lr) * K_TOT + lk * 8;

  // B producer: thread (p = t>>4, q = t&15) owns 4 channels of pixel p:
  // channel-group cg = q>>1, half = q&1 -> channels cg*8+half*4 .. +4.
  int pp = t >> 4, qq = t & 15;
  int cgp = qq >> 1, half = qq & 1;
  int bofs = pp * 64 + ((cgp ^ (pp & 7)) << 3) + (half << 2);  // swizzled elem offset
  int cb4 = (cgp << 3) + (half << 2);                           // channel offset in 64-chunk

  u16 *Bc = &Bs[0][0], *Bn = &Bs[1][0], *Bf = &Bs[2][0];

  __syncthreads();   // phase-0 tables ready

  us4 aq0, aq1, aq2, aq3, bq0, bq1, bq2, bq3;
  float aw0, aw1, aw2, aw3, bw0, bw1, bw2, bw3;
  float tw0, tw1, tw2, tw3;
  int ti0, ti1, ti2, ti3;
  short8 ua00, ua01, ua10, ua11, ub00, ub01, ub10, ub11;

  // prologue: A(0)->ua; B(0) produced into Bc; q(1)->slot b
  ALOAD(0, ua);
  PLOAD_S(0, a);
  PFIN_S(a, Bc);
  PLOAD_S(1, b);
  CBAR();

  // main loop: tiles 0..33, 2-unrolled for reg-slot parity
#pragma unroll 1
  for (int it = 0; it < 17; ++it) {
    // even sub-iter s=2it: compute tile s (ua); A(s+1)->ub; produce B(s+1)
    // from q-slot b; q(s+2)->slot a
    ALOAD(2 * it + 1, ub);
    PLOAD_S(2 * it + 2, a);
    GEMM_COMPUTE(ua, Bc);
    PFIN_S(b, Bn);
    CBAR();
    ROTATE();
    // odd sub-iter s=2it+1
    ALOAD(2 * it + 2, ua);
    PLOAD_S(2 * it + 3, b);
    GEMM_COMPUTE(ub, Bc);
    PFIN_S(a, Bn);
    CBAR();
    ROTATE();
  }
  // epilogue: tiles 34, 35 (A(34) in ua from it=16 odd; q(35) in slot b)
  ALOAD(35, ub);
  GEMM_COMPUTE(ua, Bc);          // tile 34
  PFIN_S(b, Bn);                 // tile 35 B
  CBAR();
  GEMM_COMPUTE(ub, Bn);          // tile 35

  // epilogue: D mapping col = lane&15 (j), row = (lane>>4)*4 + r (o)
  int lq = lane >> 4;
#pragma unroll
  for (int oi = 0; oi < 2; oi++) {
#pragma unroll
    for (int ji = 0; ji < 2; ji++) {
      int j = j0 + wj * 32 + ji * 16 + lr;
      int bb_ = j >> 12, hw = j & (HW - 1);
      int o0 = wo * 32 + oi * 16 + lq * 4;
#pragma unroll
      for (int r = 0; r < 4; r++) {
        size_t oidx = (((size_t)(bb_ * C_CH + o0 + r)) << 12) + hw;
        float v = acc[oi][ji][r];
        v = fmaxf(v, 0.f);
        float ft = isbf ? b2f(((const u16*)featv)[oidx]) : ((const float*)featv)[oidx];
        v = fmaxf(v + ft, 0.f);
        if (isbf) ((u16*)outv)[oidx] = f2b(v);
        else      ((float*)outv)[oidx] = v;
      }
    }
  }
}

extern "C" void kernel_launch(void* const* d_in, const int* in_sizes, int n_in,
                              void* d_out, int out_size, void* d_ws, size_t ws_size,
                              hipStream_t stream) {
  const void* feat = d_in[0];
  const void* offs = d_in[1];
  const void* wght = d_in[2];

  // workspace layout (256B-aligned sections)
  const size_t off_flag = 0;
  const size_t off_wr   = 256;                          // bf16 Wr, 1.125 MB
  const size_t off_ftr  = off_wr + (size_t)1179648;     // bf16 channels-last feature, 8 MB
  const size_t need     = off_ftr + (size_t)8388608;
  if (ws_size < need) return;  // insufficient scratch; cannot run

  char* ws = (char*)d_ws;
  int* flag = (int*)(ws + off_flag);
  u16* Wr   = (u16*)(ws + off_wr);
  u16* ftr  = (u16*)(ws + off_ftr);

  k_detect<<<1, 256, 0, stream>>>((const u16*)feat, flag);
  k_prep<<<dim3(128, 8, 5), dim3(32, 8), 0, stream>>>(feat, ftr, wght, Wr, flag);
  k_gemm<<<J_TOT / 64, 1024, 0, stream>>>(Wr, ftr, offs, feat, d_out, flag);
}

// Round 10
// 135.001 us; speedup vs baseline: 1.2564x; 1.2564x over previous
//
#include <hip/hip_runtime.h>

// Problem constants: B=4, C=256, H=W=64, KS=3, N=9
#define HW    4096
#define J_TOT 16384   // B*H*W
#define K_TOT 2304    // 9*256
#define C_CH  256

typedef unsigned short u16;
typedef unsigned int   u32;
typedef __attribute__((ext_vector_type(8))) short short8;   // 8 bf16 (4 VGPRs), MFMA A/B frag
typedef __attribute__((ext_vector_type(4))) float f32x4;    // MFMA C/D frag

__device__ __forceinline__ float b2f(u16 u) { return __uint_as_float(((u32)u) << 16); }
__device__ __forceinline__ u16 f2b(float x) {             // RNE f32->bf16
  u32 u = __float_as_uint(x);
  u += 0x7FFFu + ((u >> 16) & 1u);
  return (u16)(u >> 16);
}

// async global->LDS, 16B per lane; lds dst must be wave-uniform base (+lane*16 implicit)
__device__ __forceinline__ void gload_lds16(const u16* g, u16* l) {
  __builtin_amdgcn_global_load_lds(
      (__attribute__((address_space(1))) void*)(void*)g,
      (__attribute__((address_space(3))) void*)(void*)l, 16, 0, 0);
}

// ---------------------------------------------------------------------------
// Kernel 0 (FALLBACK ONLY -- launched only if in_sizes is ambiguous):
// dtype detection (1 = bf16 inputs, 0 = f32 inputs).
// ---------------------------------------------------------------------------
__global__ void k_detect(const u16* __restrict__ f, int* __restrict__ flag) {
  __shared__ int sh[256];
  int t = threadIdx.x;
  int hits = 0;
  for (int i = t; i < 2048; i += 256) {
    u16 u = f[2 * i];
    int e = (u >> 7) & 0xFF;
    hits += (e >= 100 && e <= 141) ? 1 : 0;
  }
  sh[t] = hits;
  __syncthreads();
  if (t == 0) {
    int s = 0;
    for (int i = 0; i < 256; i++) s += sh[i];
    flag[0] = (s > 1024) ? 1 : 0;
  }
}

// ---------------------------------------------------------------------------
// Kernel 1 (merged prep): z<4 -> feature (b,c,h,w) -> channels-last bf16
// ftr[b][hw][c] (b = blockIdx.z); z==4 -> weight (o,c,3,3) -> Wr[o][k],
// k = n*256+c, via LDS so both global reads and writes are coalesced
// (was: stride-9 scattered reads).
// ---------------------------------------------------------------------------
__global__ void k_prep(const void* __restrict__ featv, u16* __restrict__ ftr,
                       const void* __restrict__ wv, u16* __restrict__ Wr,
                       const int* __restrict__ flag, int isbf_h) {
  int isbf = (isbf_h >= 0) ? isbf_h : *flag;
  int tx = threadIdx.x;  // 0..31
  int ty = threadIdx.y;  // 0..7
  int z = blockIdx.z;
  if (z < 4) {
    __shared__ u16 tile[32][33];
    int b = z;
    int hw0 = blockIdx.x << 5;
    int c0 = blockIdx.y << 5;
    if (isbf) {
      const u16* f = (const u16*)featv;
#pragma unroll
      for (int i = 0; i < 4; i++) {
        int c = c0 + ty + i * 8;
        tile[ty + i * 8][tx] = f[(((size_t)(b * C_CH + c)) << 12) + hw0 + tx];
      }
    } else {
      const float* f = (const float*)featv;
#pragma unroll
      for (int i = 0; i < 4; i++) {
        int c = c0 + ty + i * 8;
        tile[ty + i * 8][tx] = f2b(f[(((size_t)(b * C_CH + c)) << 12) + hw0 + tx]);
      }
    }
    __syncthreads();
#pragma unroll
    for (int i = 0; i < 4; i++) {
      int hw = hw0 + ty + i * 8;
      ftr[(((size_t)(b * HW + hw)) << 8) + c0 + tx] = tile[tx][ty + i * 8];
    }
  } else {
    // weight repack: block = one output channel o; read o-slice (2304 elems,
    // contiguous, elem idx = c*9+n), LDS-transpose, write 9 contiguous
    // 256-elem segments (dst k = n*256+c).
    __shared__ u16 wtile[2304];
    int bid = blockIdx.x + (blockIdx.y << 7);   // 0..1023
    if (bid >= C_CH) return;
    int flat = ty * 32 + tx;                    // 0..255
    if (isbf) {
      const u16* wsrc = (const u16*)wv + (size_t)bid * K_TOT;
      for (int i = flat; i < K_TOT; i += 256) wtile[i] = wsrc[i];
    } else {
      const float* wsrc = (const float*)wv + (size_t)bid * K_TOT;
      for (int i = flat; i < K_TOT; i += 256) wtile[i] = f2b(wsrc[i]);
    }
    __syncthreads();
    u16* wdst = Wr + (size_t)bid * K_TOT;
#pragma unroll
    for (int n = 0; n < 9; n++) wdst[n * 256 + flat] = wtile[flat * 9 + n];
  }
}

// ---------------------------------------------------------------------------
// Kernel 2 (FUSED gather+GEMM): r8 structure (best measured: 55.4us gemm).
// A-direct (r7/r9) is DEAD: both schedules regressed ~+41us with identical
// counters -- per-wave A loads duplicate the Wr hot-set and saturate the
// per-XCD L2 channels; gload_lds DMA (1 request/line/CU, LDS-shared) is the
// minimum-traffic A path. This round's deltas are all outside the K-loop
// schedule: exact host-dtype (no flag load in common path), prologue
// vmcnt(4) (retires buffer-0 A-DMA before first compute), pair-wise PFIN
// unpack (bit-exact, ~16 fewer VALU/thread/tile).
//
// Structure: block 64j x 256o, 1024 thr = 16 waves (2j x 8o), wave tile
// 32jx32o, grid 256 = 1 block/CU = 4 waves/SIMD. XCD-chunked swizzle
// (FETCH 3x cut, r8). A (Wr) via gload_lds16 DMA, triple-buffered; B
// produced in LDS by bilinear interp (dup-1); np-cadenced table cache;
// counted barrier vmcnt(6)+lgkmcnt(0) (per wave per iter exactly 6 VMEM:
// 4 corner q + 2 A-DMA; retires last iter's). Swizzle slot cg^(p&7),
// reader g^(row&7): 0 conflicts measured.
// ---------------------------------------------------------------------------
#define NT 36   // K_TOT / 64

#define A_DMA(Ab)                                                            \
  do {                                                                       \
    gload_lds16(asrc0, (Ab) + wave * 1024);                                  \
    gload_lds16(asrc1, (Ab) + wave * 1024 + 512);                            \
    asrc0 += 64; asrc1 += 64;                                                \
  } while (0)

// load corner q-regs + snapshot weights for `tile` into slot P (a or b)
#define PLOAD_S(tile, P)                                                     \
  do {                                                                       \
    if (((tile) & 3) == 0) {                                                 \
      int np_ = (tile) >> 2;                                                 \
      tw0 = gs[np_][0][pp]; tw1 = gs[np_][1][pp];                            \
      tw2 = gs[np_][2][pp]; tw3 = gs[np_][3][pp];                            \
      ti0 = isx[np_][0][pp]; ti1 = isx[np_][1][pp];                          \
      ti2 = isx[np_][2][pp]; ti3 = isx[np_][3][pp];                          \
    }                                                                        \
    int c0_ = (((tile) & 3) << 6) + cb4;                                     \
    P##w0 = tw0; P##w1 = tw1; P##w2 = tw2; P##w3 = tw3;                      \
    P##q0 = *(const uint2*)(ftr + ti0 + c0_);                                \
    P##q1 = *(const uint2*)(ftr + ti1 + c0_);                                \
    P##q2 = *(const uint2*)(ftr + ti2 + c0_);                                \
    P##q3 = *(const uint2*)(ftr + ti3 + c0_);                                \
  } while (0)

// bilinear interp of 4 channels + pack to bf16 + swizzled ds_write.
// Pair-wise unpack is bit-exact vs element b2f: lo = w<<16, hi = w&0xFFFF0000.
#define PFIN_S(P, Bb)                                                        \
  do {                                                                       \
    float c0l = __uint_as_float(P##q0.x << 16);                              \
    float c0h = __uint_as_float(P##q0.x & 0xFFFF0000u);                      \
    float c1l = __uint_as_float(P##q1.x << 16);                              \
    float c1h = __uint_as_float(P##q1.x & 0xFFFF0000u);                      \
    float c2l = __uint_as_float(P##q2.x << 16);                              \
    float c2h = __uint_as_float(P##q2.x & 0xFFFF0000u);                      \
    float c3l = __uint_as_float(P##q3.x << 16);                              \
    float c3h = __uint_as_float(P##q3.x & 0xFFFF0000u);                      \
    float v0 = P##w0 * c0l + P##w1 * c1l + P##w2 * c2l + P##w3 * c3l;        \
    float v1 = P##w0 * c0h + P##w1 * c1h + P##w2 * c2h + P##w3 * c3h;        \
    c0l = __uint_as_float(P##q0.y << 16);                                    \
    c0h = __uint_as_float(P##q0.y & 0xFFFF0000u);                            \
    c1l = __uint_as_float(P##q1.y << 16);                                    \
    c1h = __uint_as_float(P##q1.y & 0xFFFF0000u);                            \
    c2l = __uint_as_float(P##q2.y << 16);                                    \
    c2h = __uint_as_float(P##q2.y & 0xFFFF0000u);                            \
    c3l = __uint_as_float(P##q3.y << 16);                                    \
    c3h = __uint_as_float(P##q3.y & 0xFFFF0000u);                            \
    float v2 = P##w0 * c0l + P##w1 * c1l + P##w2 * c2l + P##w3 * c3l;        \
    float v3 = P##w0 * c0h + P##w1 * c1h + P##w2 * c2h + P##w3 * c3h;        \
    uint2 ov_;                                                               \
    ov_.x = (u32)f2b(v0) | ((u32)f2b(v1) << 16);                             \
    ov_.y = (u32)f2b(v2) | ((u32)f2b(v3) << 16);                             \
    *(uint2*)((Bb) + bofs) = ov_;                                            \
  } while (0)

#define GEMM_COMPUTE(Ab, Bb)                                                 \
  do {                                                                       \
    short8 af[2][2], bf[2][2];                                               \
    _Pragma("unroll")                                                        \
    for (int kk = 0; kk < 2; kk++) {                                         \
      int go = (((kk << 2) + lk) ^ swz) << 3;                                \
      _Pragma("unroll")                                                      \
      for (int oi = 0; oi < 2; oi++)                                         \
        af[oi][kk] = *(const short8*)((Ab) + (wo * 32 + oi * 16 + lr) * 64 + go); \
      _Pragma("unroll")                                                      \
      for (int ji = 0; ji < 2; ji++)                                         \
        bf[ji][kk] = *(const short8*)((Bb) + (wj * 32 + ji * 16 + lr) * 64 + go); \
    }                                                                        \
    __builtin_amdgcn_s_setprio(1);                                           \
    _Pragma("unroll")                                                        \
    for (int kk = 0; kk < 2; kk++)                                           \
      _Pragma("unroll")                                                      \
      for (int oi = 0; oi < 2; oi++)                                         \
        _Pragma("unroll")                                                    \
        for (int ji = 0; ji < 2; ji++)                                       \
          acc[oi][ji] = __builtin_amdgcn_mfma_f32_16x16x32_bf16(             \
              af[oi][kk], bf[ji][kk], acc[oi][ji], 0, 0, 0);                 \
    __builtin_amdgcn_s_setprio(0);                                           \
  } while (0)

#define CBAR()                                                               \
  do {                                                                       \
    asm volatile("s_waitcnt vmcnt(6) lgkmcnt(0)" ::: "memory");              \
    __builtin_amdgcn_s_barrier();                                            \
  } while (0)

#define ROTATE()                                                             \
  do {                                                                       \
    u16* tp_ = Ac; Ac = An; An = Af; Af = tp_;                               \
    tp_ = Bc; Bc = Bn; Bn = Bf; Bf = tp_;                                    \
  } while (0)

__global__ __launch_bounds__(1024, 4) void k_gemm(const u16* __restrict__ Wr,
                                                  const u16* __restrict__ ftr,
                                                  const void* __restrict__ offv,
                                                  const void* __restrict__ featv,
                                                  void* __restrict__ outv,
                                                  const int* __restrict__ flag,
                                                  int isbf_h) {
  __shared__ u16 As[3][256 * 64];   // [o_row][k] 32KB x3
  __shared__ u16 Bs[3][64 * 64];    // [j_row][k]  8KB x3
  __shared__ float gs[9][4][64];    // bilinear weights, 9KB
  __shared__ int   isx[9][4][64];   // corner base offsets (elem, row<<8), 9KB
  int isbf = (isbf_h >= 0) ? isbf_h : *flag;
  if (isbf_h < 0) asm volatile("s_waitcnt vmcnt(0)" ::: "memory");  // keep vmcnt exact
  asm volatile("" :: "s"(isbf));
  // XCD-chunked bijective swizzle (nwg=256, 32 consecutive-j blocks per XCD)
  int bid = blockIdx.x;
  int xb = (bid & 7) * 32 + (bid >> 3);
  int j0 = xb << 6;
  int b = j0 >> 12;
  int hw0 = j0 & (HW - 1);
  int t = threadIdx.x;
  int wave = t >> 6, lane = t & 63;
  int wj = wave >> 3, wo = wave & 7;    // 2j x 8o wave grid
  int lr = lane & 15, lk = lane >> 4;
  int swz = lr & 7;

  // ---- phase 0: corner indices + weights for 64 pixels x 9 n (verified) ----
  if (t < 576) {
    int n = t >> 6, p = t & 63;
    int hw = hw0 + p;
    int h = hw >> 6, w = hw & 63;
    size_t obi = (((size_t)(b * 18 + n)) << 12) + hw;
    float ox, oy;
    if (isbf) {
      const u16* po = (const u16*)offv;
      ox = b2f(po[obi]);
      oy = b2f(po[obi + (9u << 12)]);
    } else {
      const float* po = (const float*)offv;
      ox = po[obi];
      oy = po[obi + (9u << 12)];
    }
    int ki = n / 3, kj = n % 3;
    float px = (float)(h + ki) + ox;
    float py = (float)(w + kj) + oy;
    float fx = floorf(px), fy = floorf(py);
    float qltx = fminf(fmaxf(fx, 0.f), 65.f);
    float qlty = fminf(fmaxf(fy, 0.f), 65.f);
    float qrbx = fminf(fmaxf(fx + 1.f, 0.f), 65.f);
    float qrby = fminf(fmaxf(fy + 1.f, 0.f), 65.f);
    float pcx = fminf(fmaxf(px, 0.f), 65.f);
    float pcy = fminf(fmaxf(py, 0.f), 65.f);
    float dltx = 1.f + (qltx - pcx);
    float drbx = 1.f - (qrbx - pcx);
    float dlty = 1.f + (qlty - pcy);
    float drby = 1.f - (qrby - pcy);
    float g0 = dltx * dlty;   // (q_lt_x, q_lt_y)
    float g1 = drbx * drby;   // (q_rb_x, q_rb_y)
    float g2 = dltx * drby;   // (q_lt_x, q_rb_y)
    float g3 = drbx * dlty;   // (q_rb_x, q_lt_y)
    int x0 = (int)qltx, y0 = (int)qlty, x1 = (int)qrbx, y1 = (int)qrby;
    int v0 = (x0 >= 1 && x0 <= 64 && y0 >= 1 && y0 <= 64);
    int v1 = (x1 >= 1 && x1 <= 64 && y1 >= 1 && y1 <= 64);
    int v2 = (x0 >= 1 && x0 <= 64 && y1 >= 1 && y1 <= 64);
    int v3 = (x1 >= 1 && x1 <= 64 && y0 >= 1 && y0 <= 64);
    int base = b << 12;
    isx[n][0][p] = v0 ? ((base + ((x0 - 1) << 6) + (y0 - 1)) << 8) : 0;
    isx[n][1][p] = v1 ? ((base + ((x1 - 1) << 6) + (y1 - 1)) << 8) : 0;
    isx[n][2][p] = v2 ? ((base + ((x0 - 1) << 6) + (y1 - 1)) << 8) : 0;
    isx[n][3][p] = v3 ? ((base + ((x1 - 1) << 6) + (y0 - 1)) << 8) : 0;
    gs[n][0][p] = v0 ? g0 : 0.f;
    gs[n][1][p] = v1 ? g1 : 0.f;
    gs[n][2][p] = v2 ? g2 : 0.f;
    gs[n][3][p] = v3 ? g3 : 0.f;
  }

  f32x4 acc[2][2];   // [oi][ji]
  f32x4 zero = {0.f, 0.f, 0.f, 0.f};
#pragma unroll
  for (int i = 0; i < 2; i++)
#pragma unroll
    for (int j = 0; j < 2; j++) acc[i][j] = zero;

  // A staging: wave w stages rows [16w,16w+16) of the 256 o-rows via 2
  // instrs; lane l covers row +(l>>3), source col-group pre-swizzled
  // (l&7)^(l>>3) so LDS slot (r,cg) holds global column (cg ^ (r&7)).
  int rb = lane >> 3;
  int cs = ((lane & 7) ^ rb) << 3;
  const u16* asrc0 = Wr + (size_t)(wave * 16 + 0 + rb) * K_TOT + cs;
  const u16* asrc1 = Wr + (size_t)(wave * 16 + 8 + rb) * K_TOT + cs;

  // B producer: thread (p = t>>4, q = t&15) owns 4 channels of pixel p:
  // channel-group cg = q>>1, half = q&1 -> channels cg*8+half*4 .. +4.
  int pp = t >> 4, qq = t & 15;
  int cgp = qq >> 1, half = qq & 1;
  int bofs = pp * 64 + ((cgp ^ (pp & 7)) << 3) + (half << 2);  // swizzled elem offset
  int cb4 = (cgp << 3) + (half << 2);                           // channel offset in 64-chunk

  u16 *Ac = &As[0][0], *An = &As[1][0], *Af = &As[2][0];
  u16 *Bc = &Bs[0][0], *Bn = &Bs[1][0], *Bf = &Bs[2][0];

  __syncthreads();   // phase-0 tables ready

  uint2 aq0, aq1, aq2, aq3, bq0, bq1, bq2, bq3;
  float aw0, aw1, aw2, aw3, bw0, bw1, bw2, bw3;
  float tw0, tw1, tw2, tw3;
  int ti0, ti1, ti2, ti3;

  // prologue: tile0 -> cur (B produced immediately), tile1 -> nxt (A only;
  // B for tile1 produced in the first loop iteration). vmcnt(4) retires
  // tile0's A-DMA (2) before first compute; q(1)'s 4 loads stay in flight.
  PLOAD_S(0, a); A_DMA(Ac);
  PFIN_S(a, Bc);
  PLOAD_S(1, b); A_DMA(An);
  asm volatile("s_waitcnt vmcnt(4) lgkmcnt(0)" ::: "memory");
  __builtin_amdgcn_s_barrier();

  // main loop: 34 sub-iters (tiles 0..33 computed), 2-unrolled for slot parity
#pragma unroll 1
  for (int it = 0; it < 17; ++it) {
    // even sub-iter: compute tile 2*it, produce B tile 2*it+1, prefetch 2*it+2
    PLOAD_S(2 * it + 2, a);
    A_DMA(Af);
    GEMM_COMPUTE(Ac, Bc);
    PFIN_S(b, Bn);
    CBAR();
    ROTATE();
    // odd sub-iter
    PLOAD_S(2 * it + 3, b);
    A_DMA(Af);
    GEMM_COMPUTE(Ac, Bc);
    PFIN_S(a, Bn);
    CBAR();
    ROTATE();
  }
  // epilogue: tiles 34, 35
  GEMM_COMPUTE(Ac, Bc);          // tile 34
  PFIN_S(b, Bn);                 // tile 35 B (slot b loaded at sub-iter tt=33)
  asm volatile("s_waitcnt vmcnt(0) lgkmcnt(0)" ::: "memory");
  __builtin_amdgcn_s_barrier();
  GEMM_COMPUTE(An, Bn);          // tile 35

  // epilogue: D mapping col = lane&15 (j), row = (lane>>4)*4 + r (o)
  int lq = lane >> 4;
#pragma unroll
  for (int oi = 0; oi < 2; oi++) {
#pragma unroll
    for (int ji = 0; ji < 2; ji++) {
      int j = j0 + wj * 32 + ji * 16 + lr;
      int bb_ = j >> 12, hw = j & (HW - 1);
      int o0 = wo * 32 + oi * 16 + lq * 4;
#pragma unroll
      for (int r = 0; r < 4; r++) {
        size_t oidx = (((size_t)(bb_ * C_CH + o0 + r)) << 12) + hw;
        float v = acc[oi][ji][r];
        v = fmaxf(v, 0.f);
        float ft = isbf ? b2f(((const u16*)featv)[oidx]) : ((const float*)featv)[oidx];
        v = fmaxf(v + ft, 0.f);
        if (isbf) ((u16*)outv)[oidx] = f2b(v);
        else      ((float*)outv)[oidx] = v;
      }
    }
  }
}

extern "C" void kernel_launch(void* const* d_in, const int* in_sizes, int n_in,
                              void* d_out, int out_size, void* d_ws, size_t ws_size,
                              hipStream_t stream) {
  const void* feat = d_in[0];
  const void* offs = d_in[1];
  const void* wght = d_in[2];

  // workspace layout (256B-aligned sections)
  const size_t off_flag = 0;
  const size_t off_wr   = 256;                          // bf16 Wr, 1.125 MB
  const size_t off_ftr  = off_wr + (size_t)1179648;     // bf16 channels-last feature, 8 MB
  const size_t need     = off_ftr + (size_t)8388608;
  if (ws_size < need) return;  // insufficient scratch; cannot run

  char* ws = (char*)d_ws;
  int* flag = (int*)(ws + off_flag);
  u16* Wr   = (u16*)(ws + off_wr);
  u16* ftr  = (u16*)(ws + off_ftr);

  // Host-side dtype detection from input byte sizes (feature: 4*256*64*64
  // elems; f32 = 16777216 B, bf16 = 8388608 B), cross-checked vs weight
  // (256*256*9 elems; f32 = 2359296 B, bf16 = 1179648 B). Fallback to the
  // on-device probe only if sizes are ambiguous (e.g. element counts).
  int isbf_h = -1;
  if (in_sizes && n_in >= 3) {
    if (in_sizes[0] == 16777216 && in_sizes[2] == 2359296) isbf_h = 0;
    else if (in_sizes[0] == 8388608 && in_sizes[2] == 1179648) isbf_h = 1;
  }
  if (isbf_h < 0)
    k_detect<<<1, 256, 0, stream>>>((const u16*)feat, flag);
  k_prep<<<dim3(128, 8, 5), dim3(32, 8), 0, stream>>>(feat, ftr, wght, Wr, flag, isbf_h);
  k_gemm<<<J_TOT / 64, 1024, 0, stream>>>(Wr, ftr, offs, feat, d_out, flag, isbf_h);
}

// Round 11
// 131.243 us; speedup vs baseline: 1.2923x; 1.0286x over previous
//
#include <hip/hip_runtime.h>

// Problem constants: B=4, C=256, H=W=64, KS=3, N=9
#define HW    4096
#define J_TOT 16384   // B*H*W
#define K_TOT 2304    // 9*256
#define C_CH  256

typedef unsigned short u16;
typedef unsigned int   u32;
typedef __attribute__((ext_vector_type(8))) short short8;   // 8 bf16 (4 VGPRs), MFMA A/B frag
typedef __attribute__((ext_vector_type(4))) float f32x4;    // MFMA C/D frag
typedef __attribute__((ext_vector_type(4))) unsigned short us4;

__device__ __forceinline__ float b2f(u16 u) { return __uint_as_float(((u32)u) << 16); }
__device__ __forceinline__ u16 f2b(float x) {             // RNE f32->bf16
  u32 u = __float_as_uint(x);
  u += 0x7FFFu + ((u >> 16) & 1u);
  return (u16)(u >> 16);
}

// async global->LDS, 16B per lane; lds dst must be wave-uniform base (+lane*16 implicit)
__device__ __forceinline__ void gload_lds16(const u16* g, u16* l) {
  __builtin_amdgcn_global_load_lds(
      (__attribute__((address_space(1))) void*)(void*)g,
      (__attribute__((address_space(3))) void*)(void*)l, 16, 0, 0);
}

// ---------------------------------------------------------------------------
// Kernel 0 (FALLBACK ONLY -- launched only if in_sizes is ambiguous):
// dtype detection (1 = bf16 inputs, 0 = f32 inputs).
// ---------------------------------------------------------------------------
__global__ void k_detect(const u16* __restrict__ f, int* __restrict__ flag) {
  __shared__ int sh[256];
  int t = threadIdx.x;
  int hits = 0;
  for (int i = t; i < 2048; i += 256) {
    u16 u = f[2 * i];
    int e = (u >> 7) & 0xFF;
    hits += (e >= 100 && e <= 141) ? 1 : 0;
  }
  sh[t] = hits;
  __syncthreads();
  if (t == 0) {
    int s = 0;
    for (int i = 0; i < 256; i++) s += sh[i];
    flag[0] = (s > 1024) ? 1 : 0;
  }
}

// ---------------------------------------------------------------------------
// Kernel 1 (merged prep): z<4 -> feature (b,c,h,w) -> channels-last bf16
// ftr[b][hw][c] (b = blockIdx.z); z==4 -> weight (o,c,3,3) -> Wr[o][k],
// k = n*256+c, via LDS so both global reads and writes are coalesced.
// ---------------------------------------------------------------------------
__global__ void k_prep(const void* __restrict__ featv, u16* __restrict__ ftr,
                       const void* __restrict__ wv, u16* __restrict__ Wr,
                       const int* __restrict__ flag, int isbf_h) {
  int isbf = (isbf_h >= 0) ? isbf_h : *flag;
  int tx = threadIdx.x;  // 0..31
  int ty = threadIdx.y;  // 0..7
  int z = blockIdx.z;
  if (z < 4) {
    __shared__ u16 tile[32][33];
    int b = z;
    int hw0 = blockIdx.x << 5;
    int c0 = blockIdx.y << 5;
    if (isbf) {
      const u16* f = (const u16*)featv;
#pragma unroll
      for (int i = 0; i < 4; i++) {
        int c = c0 + ty + i * 8;
        tile[ty + i * 8][tx] = f[(((size_t)(b * C_CH + c)) << 12) + hw0 + tx];
      }
    } else {
      const float* f = (const float*)featv;
#pragma unroll
      for (int i = 0; i < 4; i++) {
        int c = c0 + ty + i * 8;
        tile[ty + i * 8][tx] = f2b(f[(((size_t)(b * C_CH + c)) << 12) + hw0 + tx]);
      }
    }
    __syncthreads();
#pragma unroll
    for (int i = 0; i < 4; i++) {
      int hw = hw0 + ty + i * 8;
      ftr[(((size_t)(b * HW + hw)) << 8) + c0 + tx] = tile[tx][ty + i * 8];
    }
  } else {
    // weight repack: block = one output channel o; read o-slice (2304 elems,
    // contiguous, elem idx = c*9+n), LDS-transpose, write 9 contiguous
    // 256-elem segments (dst k = n*256+c).
    __shared__ u16 wtile[2304];
    int bid = blockIdx.x + (blockIdx.y << 7);   // 0..1023
    if (bid >= C_CH) return;
    int flat = ty * 32 + tx;                    // 0..255
    if (isbf) {
      const u16* wsrc = (const u16*)wv + (size_t)bid * K_TOT;
      for (int i = flat; i < K_TOT; i += 256) wtile[i] = wsrc[i];
    } else {
      const float* wsrc = (const float*)wv + (size_t)bid * K_TOT;
      for (int i = flat; i < K_TOT; i += 256) wtile[i] = f2b(wsrc[i]);
    }
    __syncthreads();
    u16* wdst = Wr + (size_t)bid * K_TOT;
#pragma unroll
    for (int n = 0; n < 9; n++) wdst[n * 256 + flat] = wtile[flat * 9 + n];
  }
}

// ---------------------------------------------------------------------------
// Kernel 2 (FUSED gather+GEMM): r8 K-loop restored BYTE-FOR-BYTE (best
// measured: 55.4us). r10's hot-loop deltas (pair-wise PFIN, prologue
// vmcnt(4)) regressed to ~64us with identical VALU/MFMA absolute time =>
// pure added stall from schedule perturbation; both reverted. Kept from
// r10 (cold path only): host-side dtype (drops the k_detect launch, ~10us
// per r3->r4 launch evidence) and coalesced weight repack.
//
// Structure: block 64j x 256o, 1024 thr = 16 waves (2j x 8o), wave tile
// 32jx32o, grid 256 = 1 block/CU = 4 waves/SIMD. XCD-chunked swizzle
// (FETCH 3x cut). A (Wr) via gload_lds16 DMA, triple-buffered (A-direct
// global->VGPR is DEAD: r7/r9 both +41us, per-XCD L2 channel saturation);
// B produced in LDS by bilinear interp (dup-1); np-cadenced table cache;
// counted barrier vmcnt(6)+lgkmcnt(0) (per wave per iter exactly 6 VMEM:
// 4 corner q + 2 A-DMA; retires last iter's). Swizzle slot cg^(p&7),
// reader g^(row&7): 0 conflicts measured.
// ---------------------------------------------------------------------------
#define NT 36   // K_TOT / 64

#define A_DMA(Ab)                                                            \
  do {                                                                       \
    gload_lds16(asrc0, (Ab) + wave * 1024);                                  \
    gload_lds16(asrc1, (Ab) + wave * 1024 + 512);                            \
    asrc0 += 64; asrc1 += 64;                                                \
  } while (0)

// load corner q-regs + snapshot weights for `tile` into slot P (a or b)
#define PLOAD_S(tile, P)                                                     \
  do {                                                                       \
    if (((tile) & 3) == 0) {                                                 \
      int np_ = (tile) >> 2;                                                 \
      tw0 = gs[np_][0][pp]; tw1 = gs[np_][1][pp];                            \
      tw2 = gs[np_][2][pp]; tw3 = gs[np_][3][pp];                            \
      ti0 = isx[np_][0][pp]; ti1 = isx[np_][1][pp];                          \
      ti2 = isx[np_][2][pp]; ti3 = isx[np_][3][pp];                          \
    }                                                                        \
    int c0_ = (((tile) & 3) << 6) + cb4;                                     \
    P##w0 = tw0; P##w1 = tw1; P##w2 = tw2; P##w3 = tw3;                      \
    P##q0 = *(const us4*)(ftr + ti0 + c0_);                                  \
    P##q1 = *(const us4*)(ftr + ti1 + c0_);                                  \
    P##q2 = *(const us4*)(ftr + ti2 + c0_);                                  \
    P##q3 = *(const us4*)(ftr + ti3 + c0_);                                  \
  } while (0)

#define PFIN_S(P, Bb)                                                        \
  do {                                                                       \
    us4 ov;                                                                  \
    _Pragma("unroll")                                                        \
    for (int i = 0; i < 4; i++) {                                            \
      float v = P##w0 * b2f(P##q0[i]) + P##w1 * b2f(P##q1[i]) +              \
                P##w2 * b2f(P##q2[i]) + P##w3 * b2f(P##q3[i]);               \
      ov[i] = f2b(v);                                                        \
    }                                                                        \
    *(us4*)((Bb) + bofs) = ov;                                               \
  } while (0)

#define GEMM_COMPUTE(Ab, Bb)                                                 \
  do {                                                                       \
    short8 af[2][2], bf[2][2];                                               \
    _Pragma("unroll")                                                        \
    for (int kk = 0; kk < 2; kk++) {                                         \
      int go = (((kk << 2) + lk) ^ swz) << 3;                                \
      _Pragma("unroll")                                                      \
      for (int oi = 0; oi < 2; oi++)                                         \
        af[oi][kk] = *(const short8*)((Ab) + (wo * 32 + oi * 16 + lr) * 64 + go); \
      _Pragma("unroll")                                                      \
      for (int ji = 0; ji < 2; ji++)                                         \
        bf[ji][kk] = *(const short8*)((Bb) + (wj * 32 + ji * 16 + lr) * 64 + go); \
    }                                                                        \
    __builtin_amdgcn_s_setprio(1);                                           \
    _Pragma("unroll")                                                        \
    for (int kk = 0; kk < 2; kk++)                                           \
      _Pragma("unroll")                                                      \
      for (int oi = 0; oi < 2; oi++)                                         \
        _Pragma("unroll")                                                    \
        for (int ji = 0; ji < 2; ji++)                                       \
          acc[oi][ji] = __builtin_amdgcn_mfma_f32_16x16x32_bf16(             \
              af[oi][kk], bf[ji][kk], acc[oi][ji], 0, 0, 0);                 \
    __builtin_amdgcn_s_setprio(0);                                           \
  } while (0)

#define CBAR()                                                               \
  do {                                                                       \
    asm volatile("s_waitcnt vmcnt(6) lgkmcnt(0)" ::: "memory");              \
    __builtin_amdgcn_s_barrier();                                            \
  } while (0)

#define ROTATE()                                                             \
  do {                                                                       \
    u16* tp_ = Ac; Ac = An; An = Af; Af = tp_;                               \
    tp_ = Bc; Bc = Bn; Bn = Bf; Bf = tp_;                                    \
  } while (0)

__global__ __launch_bounds__(1024, 4) void k_gemm(const u16* __restrict__ Wr,
                                                  const u16* __restrict__ ftr,
                                                  const void* __restrict__ offv,
                                                  const void* __restrict__ featv,
                                                  void* __restrict__ outv,
                                                  const int* __restrict__ flag,
                                                  int isbf_h) {
  __shared__ u16 As[3][256 * 64];   // [o_row][k] 32KB x3
  __shared__ u16 Bs[3][64 * 64];    // [j_row][k]  8KB x3
  __shared__ float gs[9][4][64];    // bilinear weights, 9KB
  __shared__ int   isx[9][4][64];   // corner base offsets (elem, row<<8), 9KB
  int isbf = (isbf_h >= 0) ? isbf_h : *flag;
  if (isbf_h < 0) asm volatile("s_waitcnt vmcnt(0)" ::: "memory");  // keep vmcnt exact
  asm volatile("" :: "s"(isbf));
  // XCD-chunked bijective swizzle (nwg=256, 32 consecutive-j blocks per XCD)
  int bid = blockIdx.x;
  int xb = (bid & 7) * 32 + (bid >> 3);
  int j0 = xb << 6;
  int b = j0 >> 12;
  int hw0 = j0 & (HW - 1);
  int t = threadIdx.x;
  int wave = t >> 6, lane = t & 63;
  int wj = wave >> 3, wo = wave & 7;    // 2j x 8o wave grid
  int lr = lane & 15, lk = lane >> 4;
  int swz = lr & 7;

  // ---- phase 0: corner indices + weights for 64 pixels x 9 n (verified) ----
  if (t < 576) {
    int n = t >> 6, p = t & 63;
    int hw = hw0 + p;
    int h = hw >> 6, w = hw & 63;
    size_t obi = (((size_t)(b * 18 + n)) << 12) + hw;
    float ox, oy;
    if (isbf) {
      const u16* po = (const u16*)offv;
      ox = b2f(po[obi]);
      oy = b2f(po[obi + (9u << 12)]);
    } else {
      const float* po = (const float*)offv;
      ox = po[obi];
      oy = po[obi + (9u << 12)];
    }
    int ki = n / 3, kj = n % 3;
    float px = (float)(h + ki) + ox;
    float py = (float)(w + kj) + oy;
    float fx = floorf(px), fy = floorf(py);
    float qltx = fminf(fmaxf(fx, 0.f), 65.f);
    float qlty = fminf(fmaxf(fy, 0.f), 65.f);
    float qrbx = fminf(fmaxf(fx + 1.f, 0.f), 65.f);
    float qrby = fminf(fmaxf(fy + 1.f, 0.f), 65.f);
    float pcx = fminf(fmaxf(px, 0.f), 65.f);
    float pcy = fminf(fmaxf(py, 0.f), 65.f);
    float dltx = 1.f + (qltx - pcx);
    float drbx = 1.f - (qrbx - pcx);
    float dlty = 1.f + (qlty - pcy);
    float drby = 1.f - (qrby - pcy);
    float g0 = dltx * dlty;   // (q_lt_x, q_lt_y)
    float g1 = drbx * drby;   // (q_rb_x, q_rb_y)
    float g2 = dltx * drby;   // (q_lt_x, q_rb_y)
    float g3 = drbx * dlty;   // (q_rb_x, q_lt_y)
    int x0 = (int)qltx, y0 = (int)qlty, x1 = (int)qrbx, y1 = (int)qrby;
    int v0 = (x0 >= 1 && x0 <= 64 && y0 >= 1 && y0 <= 64);
    int v1 = (x1 >= 1 && x1 <= 64 && y1 >= 1 && y1 <= 64);
    int v2 = (x0 >= 1 && x0 <= 64 && y1 >= 1 && y1 <= 64);
    int v3 = (x1 >= 1 && x1 <= 64 && y0 >= 1 && y0 <= 64);
    int base = b << 12;
    isx[n][0][p] = v0 ? ((base + ((x0 - 1) << 6) + (y0 - 1)) << 8) : 0;
    isx[n][1][p] = v1 ? ((base + ((x1 - 1) << 6) + (y1 - 1)) << 8) : 0;
    isx[n][2][p] = v2 ? ((base + ((x0 - 1) << 6) + (y1 - 1)) << 8) : 0;
    isx[n][3][p] = v3 ? ((base + ((x1 - 1) << 6) + (y0 - 1)) << 8) : 0;
    gs[n][0][p] = v0 ? g0 : 0.f;
    gs[n][1][p] = v1 ? g1 : 0.f;
    gs[n][2][p] = v2 ? g2 : 0.f;
    gs[n][3][p] = v3 ? g3 : 0.f;
  }

  f32x4 acc[2][2];   // [oi][ji]
  f32x4 zero = {0.f, 0.f, 0.f, 0.f};
#pragma unroll
  for (int i = 0; i < 2; i++)
#pragma unroll
    for (int j = 0; j < 2; j++) acc[i][j] = zero;

  // A staging: wave w stages rows [16w,16w+16) of the 256 o-rows via 2
  // instrs; lane l covers row +(l>>3), source col-group pre-swizzled
  // (l&7)^(l>>3) so LDS slot (r,cg) holds global column (cg ^ (r&7)).
  int rb = lane >> 3;
  int cs = ((lane & 7) ^ rb) << 3;
  const u16* asrc0 = Wr + (size_t)(wave * 16 + 0 + rb) * K_TOT + cs;
  const u16* asrc1 = Wr + (size_t)(wave * 16 + 8 + rb) * K_TOT + cs;

  // B producer: thread (p = t>>4, q = t&15) owns 4 channels of pixel p:
  // channel-group cg = q>>1, half = q&1 -> channels cg*8+half*4 .. +4.
  int pp = t >> 4, qq = t & 15;
  int cgp = qq >> 1, half = qq & 1;
  int bofs = pp * 64 + ((cgp ^ (pp & 7)) << 3) + (half << 2);  // swizzled elem offset
  int cb4 = (cgp << 3) + (half << 2);                           // channel offset in 64-chunk

  u16 *Ac = &As[0][0], *An = &As[1][0], *Af = &As[2][0];
  u16 *Bc = &Bs[0][0], *Bn = &Bs[1][0], *Bf = &Bs[2][0];

  __syncthreads();   // phase-0 tables ready

  us4 aq0, aq1, aq2, aq3, bq0, bq1, bq2, bq3;
  float aw0, aw1, aw2, aw3, bw0, bw1, bw2, bw3;
  float tw0, tw1, tw2, tw3;
  int ti0, ti1, ti2, ti3;

  // prologue: tile0 -> cur (B produced immediately), tile1 -> nxt (A only;
  // B for tile1 produced in the first loop iteration). vmcnt(6) retires
  // exactly tile0's A-DMA (8 outstanding -> 6, in-order) before first compute.
  PLOAD_S(0, a); A_DMA(Ac);
  PFIN_S(a, Bc);
  PLOAD_S(1, b); A_DMA(An);
  CBAR();

  // main loop: 34 sub-iters (tiles 0..33 computed), 2-unrolled for slot parity
#pragma unroll 1
  for (int it = 0; it < 17; ++it) {
    // even sub-iter: compute tile 2*it, produce B tile 2*it+1, prefetch 2*it+2
    PLOAD_S(2 * it + 2, a);
    A_DMA(Af);
    GEMM_COMPUTE(Ac, Bc);
    PFIN_S(b, Bn);
    CBAR();
    ROTATE();
    // odd sub-iter
    PLOAD_S(2 * it + 3, b);
    A_DMA(Af);
    GEMM_COMPUTE(Ac, Bc);
    PFIN_S(a, Bn);
    CBAR();
    ROTATE();
  }
  // epilogue: tiles 34, 35
  GEMM_COMPUTE(Ac, Bc);          // tile 34
  PFIN_S(b, Bn);                 // tile 35 B (slot b loaded at sub-iter tt=33)
  asm volatile("s_waitcnt vmcnt(0) lgkmcnt(0)" ::: "memory");
  __builtin_amdgcn_s_barrier();
  GEMM_COMPUTE(An, Bn);          // tile 35

  // epilogue: D mapping col = lane&15 (j), row = (lane>>4)*4 + r (o)
  int lq = lane >> 4;
#pragma unroll
  for (int oi = 0; oi < 2; oi++) {
#pragma unroll
    for (int ji = 0; ji < 2; ji++) {
      int j = j0 + wj * 32 + ji * 16 + lr;
      int bb_ = j >> 12, hw = j & (HW - 1);
      int o0 = wo * 32 + oi * 16 + lq * 4;
#pragma unroll
      for (int r = 0; r < 4; r++) {
        size_t oidx = (((size_t)(bb_ * C_CH + o0 + r)) << 12) + hw;
        float v = acc[oi][ji][r];
        v = fmaxf(v, 0.f);
        float ft = isbf ? b2f(((const u16*)featv)[oidx]) : ((const float*)featv)[oidx];
        v = fmaxf(v + ft, 0.f);
        if (isbf) ((u16*)outv)[oidx] = f2b(v);
        else      ((float*)outv)[oidx] = v;
      }
    }
  }
}

extern "C" void kernel_launch(void* const* d_in, const int* in_sizes, int n_in,
                              void* d_out, int out_size, void* d_ws, size_t ws_size,
                              hipStream_t stream) {
  const void* feat = d_in[0];
  const void* offs = d_in[1];
  const void* wght = d_in[2];

  // workspace layout (256B-aligned sections)
  const size_t off_flag = 0;
  const size_t off_wr   = 256;                          // bf16 Wr, 1.125 MB
  const size_t off_ftr  = off_wr + (size_t)1179648;     // bf16 channels-last feature, 8 MB
  const size_t need     = off_ftr + (size_t)8388608;
  if (ws_size < need) return;  // insufficient scratch; cannot run

  char* ws = (char*)d_ws;
  int* flag = (int*)(ws + off_flag);
  u16* Wr   = (u16*)(ws + off_wr);
  u16* ftr  = (u16*)(ws + off_ftr);

  // Host-side dtype detection from input byte sizes (feature: 4*256*64*64
  // elems; f32 = 16777216 B, bf16 = 8388608 B), cross-checked vs weight
  // (256*256*9 elems; f32 = 2359296 B, bf16 = 1179648 B). Fallback to the
  // on-device probe only if sizes are ambiguous (e.g. element counts).
  int isbf_h = -1;
  if (in_sizes && n_in >= 3) {
    if (in_sizes[0] == 16777216 && in_sizes[2] == 2359296) isbf_h = 0;
    else if (in_sizes[0] == 8388608 && in_sizes[2] == 1179648) isbf_h = 1;
  }
  if (isbf_h < 0)
    k_detect<<<1, 256, 0, stream>>>((const u16*)feat, flag);
  k_prep<<<dim3(128, 8, 5), dim3(32, 8), 0, stream>>>(feat, ftr, wght, Wr, flag, isbf_h);
  k_gemm<<<J_TOT / 64, 1024, 0, stream>>>(Wr, ftr, offs, feat, d_out, flag, isbf_h);
}

// Round 12
// 130.552 us; speedup vs baseline: 1.2992x; 1.0053x over previous
//
#include <hip/hip_runtime.h>

// Problem constants: B=4, C=256, H=W=64, KS=3, N=9
#define HW    4096
#define J_TOT 16384   // B*H*W
#define K_TOT 2304    // 9*256
#define C_CH  256

typedef unsigned short u16;
typedef unsigned int   u32;
typedef __attribute__((ext_vector_type(8))) short short8;   // 8 bf16 (4 VGPRs), MFMA A/B frag
typedef __attribute__((ext_vector_type(4))) float f32x4;    // MFMA C/D frag
typedef __attribute__((ext_vector_type(4))) unsigned short us4;

__device__ __forceinline__ float b2f(u16 u) { return __uint_as_float(((u32)u) << 16); }
__device__ __forceinline__ u16 f2b(float x) {             // RNE f32->bf16
  u32 u = __float_as_uint(x);
  u += 0x7FFFu + ((u >> 16) & 1u);
  return (u16)(u >> 16);
}

// async global->LDS, 16B per lane; lds dst must be wave-uniform base (+lane*16 implicit)
__device__ __forceinline__ void gload_lds16(const u16* g, u16* l) {
  __builtin_amdgcn_global_load_lds(
      (__attribute__((address_space(1))) void*)(void*)g,
      (__attribute__((address_space(3))) void*)(void*)l, 16, 0, 0);
}

// ---------------------------------------------------------------------------
// Kernel 0 (FALLBACK ONLY -- launched only if in_sizes is ambiguous):
// dtype detection (1 = bf16 inputs, 0 = f32 inputs).
// ---------------------------------------------------------------------------
__global__ void k_detect(const u16* __restrict__ f, int* __restrict__ flag) {
  __shared__ int sh[256];
  int t = threadIdx.x;
  int hits = 0;
  for (int i = t; i < 2048; i += 256) {
    u16 u = f[2 * i];
    int e = (u >> 7) & 0xFF;
    hits += (e >= 100 && e <= 141) ? 1 : 0;
  }
  sh[t] = hits;
  __syncthreads();
  if (t == 0) {
    int s = 0;
    for (int i = 0; i < 256; i++) s += sh[i];
    flag[0] = (s > 1024) ? 1 : 0;
  }
}

// ---------------------------------------------------------------------------
// Kernel 1 (merged prep): z<4 -> feature (b,c,h,w) -> channels-last bf16
// ftr[b][hw][c] (b = blockIdx.z); z==4 -> weight (o,c,3,3) -> Wr[o][k],
// k = n*256+c, via LDS so both global reads and writes are coalesced.
// ---------------------------------------------------------------------------
__global__ void k_prep(const void* __restrict__ featv, u16* __restrict__ ftr,
                       const void* __restrict__ wv, u16* __restrict__ Wr,
                       const int* __restrict__ flag, int isbf_h) {
  int isbf = (isbf_h >= 0) ? isbf_h : *flag;
  int tx = threadIdx.x;  // 0..31
  int ty = threadIdx.y;  // 0..7
  int z = blockIdx.z;
  if (z < 4) {
    __shared__ u16 tile[32][33];
    int b = z;
    int hw0 = blockIdx.x << 5;
    int c0 = blockIdx.y << 5;
    if (isbf) {
      const u16* f = (const u16*)featv;
#pragma unroll
      for (int i = 0; i < 4; i++) {
        int c = c0 + ty + i * 8;
        tile[ty + i * 8][tx] = f[(((size_t)(b * C_CH + c)) << 12) + hw0 + tx];
      }
    } else {
      const float* f = (const float*)featv;
#pragma unroll
      for (int i = 0; i < 4; i++) {
        int c = c0 + ty + i * 8;
        tile[ty + i * 8][tx] = f2b(f[(((size_t)(b * C_CH + c)) << 12) + hw0 + tx]);
      }
    }
    __syncthreads();
#pragma unroll
    for (int i = 0; i < 4; i++) {
      int hw = hw0 + ty + i * 8;
      ftr[(((size_t)(b * HW + hw)) << 8) + c0 + tx] = tile[tx][ty + i * 8];
    }
  } else {
    // weight repack: block = one output channel o; read o-slice (2304 elems,
    // contiguous, elem idx = c*9+n), LDS-transpose, write 9 contiguous
    // 256-elem segments (dst k = n*256+c).
    __shared__ u16 wtile[2304];
    int bid = blockIdx.x + (blockIdx.y << 7);   // 0..1023
    if (bid >= C_CH) return;
    int flat = ty * 32 + tx;                    // 0..255
    if (isbf) {
      const u16* wsrc = (const u16*)wv + (size_t)bid * K_TOT;
      for (int i = flat; i < K_TOT; i += 256) wtile[i] = wsrc[i];
    } else {
      const float* wsrc = (const float*)wv + (size_t)bid * K_TOT;
      for (int i = flat; i < K_TOT; i += 256) wtile[i] = f2b(wsrc[i]);
    }
    __syncthreads();
    u16* wdst = Wr + (size_t)bid * K_TOT;
#pragma unroll
    for (int n = 0; n < 9; n++) wdst[n * 256 + flat] = wtile[flat * 9 + n];
  }
}

// ---------------------------------------------------------------------------
// Kernel 2 (FUSED gather+GEMM): r8 K-loop, with isbf now a COMPILE-TIME
// constant (r11 measured 60.7 vs r8's 55.4 with a byte-identical loop; only
// delta was the runtime isbf entry path -- select + conditional asm waitcnt
// + runtime dtype branches in phase-0/epilogue). The body is a forceinline
// device function; three thin kernels instantiate it with isbf = literal 0,
// literal 1, or *flag (fallback). Common path strictly removes instructions
// vs r8: no flag load, no pin, folded branches, exact vmcnt accounting
// (prologue 12 outstanding, vmcnt(6) retires exactly tile-0's 6).
//
// Structure (unchanged, measured optimum): block 64j x 256o, 1024 thr = 16
// waves (2j x 8o), wave tile 32jx32o, grid 256 = 1 block/CU = 4 waves/SIMD.
// XCD-chunked swizzle (FETCH 3x cut). A (Wr) via gload_lds16 DMA, triple-
// buffered (A-direct global->VGPR DEAD: r7/r9 +41us, per-XCD L2 channel
// saturation). B produced in LDS by bilinear interp (dup-1); np-cadenced
// table cache; counted barrier vmcnt(6)+lgkmcnt(0); swizzle slot cg^(p&7),
// reader g^(row&7): 0 conflicts measured.
// ---------------------------------------------------------------------------
#define NT 36   // K_TOT / 64

#define A_DMA(Ab)                                                            \
  do {                                                                       \
    gload_lds16(asrc0, (Ab) + wave * 1024);                                  \
    gload_lds16(asrc1, (Ab) + wave * 1024 + 512);                            \
    asrc0 += 64; asrc1 += 64;                                                \
  } while (0)

// load corner q-regs + snapshot weights for `tile` into slot P (a or b)
#define PLOAD_S(tile, P)                                                     \
  do {                                                                       \
    if (((tile) & 3) == 0) {                                                 \
      int np_ = (tile) >> 2;                                                 \
      tw0 = gs[np_][0][pp]; tw1 = gs[np_][1][pp];                            \
      tw2 = gs[np_][2][pp]; tw3 = gs[np_][3][pp];                            \
      ti0 = isx[np_][0][pp]; ti1 = isx[np_][1][pp];                          \
      ti2 = isx[np_][2][pp]; ti3 = isx[np_][3][pp];                          \
    }                                                                        \
    int c0_ = (((tile) & 3) << 6) + cb4;                                     \
    P##w0 = tw0; P##w1 = tw1; P##w2 = tw2; P##w3 = tw3;                      \
    P##q0 = *(const us4*)(ftr + ti0 + c0_);                                  \
    P##q1 = *(const us4*)(ftr + ti1 + c0_);                                  \
    P##q2 = *(const us4*)(ftr + ti2 + c0_);                                  \
    P##q3 = *(const us4*)(ftr + ti3 + c0_);                                  \
  } while (0)

#define PFIN_S(P, Bb)                                                        \
  do {                                                                       \
    us4 ov;                                                                  \
    _Pragma("unroll")                                                        \
    for (int i = 0; i < 4; i++) {                                            \
      float v = P##w0 * b2f(P##q0[i]) + P##w1 * b2f(P##q1[i]) +              \
                P##w2 * b2f(P##q2[i]) + P##w3 * b2f(P##q3[i]);               \
      ov[i] = f2b(v);                                                        \
    }                                                                        \
    *(us4*)((Bb) + bofs) = ov;                                               \
  } while (0)

#define GEMM_COMPUTE(Ab, Bb)                                                 \
  do {                                                                       \
    short8 af[2][2], bf[2][2];                                               \
    _Pragma("unroll")                                                        \
    for (int kk = 0; kk < 2; kk++) {                                         \
      int go = (((kk << 2) + lk) ^ swz) << 3;                                \
      _Pragma("unroll")                                                      \
      for (int oi = 0; oi < 2; oi++)                                         \
        af[oi][kk] = *(const short8*)((Ab) + (wo * 32 + oi * 16 + lr) * 64 + go); \
      _Pragma("unroll")                                                      \
      for (int ji = 0; ji < 2; ji++)                                         \
        bf[ji][kk] = *(const short8*)((Bb) + (wj * 32 + ji * 16 + lr) * 64 + go); \
    }                                                                        \
    __builtin_amdgcn_s_setprio(1);                                           \
    _Pragma("unroll")                                                        \
    for (int kk = 0; kk < 2; kk++)                                           \
      _Pragma("unroll")                                                      \
      for (int oi = 0; oi < 2; oi++)                                         \
        _Pragma("unroll")                                                    \
        for (int ji = 0; ji < 2; ji++)                                       \
          acc[oi][ji] = __builtin_amdgcn_mfma_f32_16x16x32_bf16(             \
              af[oi][kk], bf[ji][kk], acc[oi][ji], 0, 0, 0);                 \
    __builtin_amdgcn_s_setprio(0);                                           \
  } while (0)

#define CBAR()                                                               \
  do {                                                                       \
    asm volatile("s_waitcnt vmcnt(6) lgkmcnt(0)" ::: "memory");              \
    __builtin_amdgcn_s_barrier();                                            \
  } while (0)

#define ROTATE()                                                             \
  do {                                                                       \
    u16* tp_ = Ac; Ac = An; An = Af; Af = tp_;                               \
    tp_ = Bc; Bc = Bn; Bn = Bf; Bf = tp_;                                    \
  } while (0)

__device__ __forceinline__ void gemm_body(const u16* __restrict__ Wr,
                                          const u16* __restrict__ ftr,
                                          const void* __restrict__ offv,
                                          const void* __restrict__ featv,
                                          void* __restrict__ outv,
                                          const int isbf) {
  __shared__ u16 As[3][256 * 64];   // [o_row][k] 32KB x3
  __shared__ u16 Bs[3][64 * 64];    // [j_row][k]  8KB x3
  __shared__ float gs[9][4][64];    // bilinear weights, 9KB
  __shared__ int   isx[9][4][64];   // corner base offsets (elem, row<<8), 9KB
  // XCD-chunked bijective swizzle (nwg=256, 32 consecutive-j blocks per XCD)
  int bid = blockIdx.x;
  int xb = (bid & 7) * 32 + (bid >> 3);
  int j0 = xb << 6;
  int b = j0 >> 12;
  int hw0 = j0 & (HW - 1);
  int t = threadIdx.x;
  int wave = t >> 6, lane = t & 63;
  int wj = wave >> 3, wo = wave & 7;    // 2j x 8o wave grid
  int lr = lane & 15, lk = lane >> 4;
  int swz = lr & 7;

  // ---- phase 0: corner indices + weights for 64 pixels x 9 n (verified) ----
  if (t < 576) {
    int n = t >> 6, p = t & 63;
    int hw = hw0 + p;
    int h = hw >> 6, w = hw & 63;
    size_t obi = (((size_t)(b * 18 + n)) << 12) + hw;
    float ox, oy;
    if (isbf) {
      const u16* po = (const u16*)offv;
      ox = b2f(po[obi]);
      oy = b2f(po[obi + (9u << 12)]);
    } else {
      const float* po = (const float*)offv;
      ox = po[obi];
      oy = po[obi + (9u << 12)];
    }
    int ki = n / 3, kj = n % 3;
    float px = (float)(h + ki) + ox;
    float py = (float)(w + kj) + oy;
    float fx = floorf(px), fy = floorf(py);
    float qltx = fminf(fmaxf(fx, 0.f), 65.f);
    float qlty = fminf(fmaxf(fy, 0.f), 65.f);
    float qrbx = fminf(fmaxf(fx + 1.f, 0.f), 65.f);
    float qrby = fminf(fmaxf(fy + 1.f, 0.f), 65.f);
    float pcx = fminf(fmaxf(px, 0.f), 65.f);
    float pcy = fminf(fmaxf(py, 0.f), 65.f);
    float dltx = 1.f + (qltx - pcx);
    float drbx = 1.f - (qrbx - pcx);
    float dlty = 1.f + (qlty - pcy);
    float drby = 1.f - (qrby - pcy);
    float g0 = dltx * dlty;   // (q_lt_x, q_lt_y)
    float g1 = drbx * drby;   // (q_rb_x, q_rb_y)
    float g2 = dltx * drby;   // (q_lt_x, q_rb_y)
    float g3 = drbx * dlty;   // (q_rb_x, q_lt_y)
    int x0 = (int)qltx, y0 = (int)qlty, x1 = (int)qrbx, y1 = (int)qrby;
    int v0 = (x0 >= 1 && x0 <= 64 && y0 >= 1 && y0 <= 64);
    int v1 = (x1 >= 1 && x1 <= 64 && y1 >= 1 && y1 <= 64);
    int v2 = (x0 >= 1 && x0 <= 64 && y1 >= 1 && y1 <= 64);
    int v3 = (x1 >= 1 && x1 <= 64 && y0 >= 1 && y0 <= 64);
    int base = b << 12;
    isx[n][0][p] = v0 ? ((base + ((x0 - 1) << 6) + (y0 - 1)) << 8) : 0;
    isx[n][1][p] = v1 ? ((base + ((x1 - 1) << 6) + (y1 - 1)) << 8) : 0;
    isx[n][2][p] = v2 ? ((base + ((x0 - 1) << 6) + (y1 - 1)) << 8) : 0;
    isx[n][3][p] = v3 ? ((base + ((x1 - 1) << 6) + (y0 - 1)) << 8) : 0;
    gs[n][0][p] = v0 ? g0 : 0.f;
    gs[n][1][p] = v1 ? g1 : 0.f;
    gs[n][2][p] = v2 ? g2 : 0.f;
    gs[n][3][p] = v3 ? g3 : 0.f;
  }

  f32x4 acc[2][2];   // [oi][ji]
  f32x4 zero = {0.f, 0.f, 0.f, 0.f};
#pragma unroll
  for (int i = 0; i < 2; i++)
#pragma unroll
    for (int j = 0; j < 2; j++) acc[i][j] = zero;

  // A staging: wave w stages rows [16w,16w+16) of the 256 o-rows via 2
  // instrs; lane l covers row +(l>>3), source col-group pre-swizzled
  // (l&7)^(l>>3) so LDS slot (r,cg) holds global column (cg ^ (r&7)).
  int rb = lane >> 3;
  int cs = ((lane & 7) ^ rb) << 3;
  const u16* asrc0 = Wr + (size_t)(wave * 16 + 0 + rb) * K_TOT + cs;
  const u16* asrc1 = Wr + (size_t)(wave * 16 + 8 + rb) * K_TOT + cs;

  // B producer: thread (p = t>>4, q = t&15) owns 4 channels of pixel p:
  // channel-group cg = q>>1, half = q&1 -> channels cg*8+half*4 .. +4.
  int pp = t >> 4, qq = t & 15;
  int cgp = qq >> 1, half = qq & 1;
  int bofs = pp * 64 + ((cgp ^ (pp & 7)) << 3) + (half << 2);  // swizzled elem offset
  int cb4 = (cgp << 3) + (half << 2);                           // channel offset in 64-chunk

  u16 *Ac = &As[0][0], *An = &As[1][0], *Af = &As[2][0];
  u16 *Bc = &Bs[0][0], *Bn = &Bs[1][0], *Bf = &Bs[2][0];

  __syncthreads();   // phase-0 tables ready

  us4 aq0, aq1, aq2, aq3, bq0, bq1, bq2, bq3;
  float aw0, aw1, aw2, aw3, bw0, bw1, bw2, bw3;
  float tw0, tw1, tw2, tw3;
  int ti0, ti1, ti2, ti3;

  // prologue: tile0 -> cur (B produced immediately), tile1 -> nxt (A only;
  // B for tile1 produced in the first loop iteration). vmcnt(6) retires
  // exactly tile0's 6 VMEM (12 outstanding -> 6, in-order) before first use.
  PLOAD_S(0, a); A_DMA(Ac);
  PFIN_S(a, Bc);
  PLOAD_S(1, b); A_DMA(An);
  CBAR();

  // main loop: 34 sub-iters (tiles 0..33 computed), 2-unrolled for slot parity
#pragma unroll 1
  for (int it = 0; it < 17; ++it) {
    // even sub-iter: compute tile 2*it, produce B tile 2*it+1, prefetch 2*it+2
    PLOAD_S(2 * it + 2, a);
    A_DMA(Af);
    GEMM_COMPUTE(Ac, Bc);
    PFIN_S(b, Bn);
    CBAR();
    ROTATE();
    // odd sub-iter
    PLOAD_S(2 * it + 3, b);
    A_DMA(Af);
    GEMM_COMPUTE(Ac, Bc);
    PFIN_S(a, Bn);
    CBAR();
    ROTATE();
  }
  // epilogue: tiles 34, 35
  GEMM_COMPUTE(Ac, Bc);          // tile 34
  PFIN_S(b, Bn);                 // tile 35 B (slot b loaded at sub-iter tt=33)
  asm volatile("s_waitcnt vmcnt(0) lgkmcnt(0)" ::: "memory");
  __builtin_amdgcn_s_barrier();
  GEMM_COMPUTE(An, Bn);          // tile 35

  // epilogue: D mapping col = lane&15 (j), row = (lane>>4)*4 + r (o)
  int lq = lane >> 4;
#pragma unroll
  for (int oi = 0; oi < 2; oi++) {
#pragma unroll
    for (int ji = 0; ji < 2; ji++) {
      int j = j0 + wj * 32 + ji * 16 + lr;
      int bb_ = j >> 12, hw = j & (HW - 1);
      int o0 = wo * 32 + oi * 16 + lq * 4;
#pragma unroll
      for (int r = 0; r < 4; r++) {
        size_t oidx = (((size_t)(bb_ * C_CH + o0 + r)) << 12) + hw;
        float v = acc[oi][ji][r];
        v = fmaxf(v, 0.f);
        float ft = isbf ? b2f(((const u16*)featv)[oidx]) : ((const float*)featv)[oidx];
        v = fmaxf(v + ft, 0.f);
        if (isbf) ((u16*)outv)[oidx] = f2b(v);
        else      ((float*)outv)[oidx] = v;
      }
    }
  }
}

__global__ __launch_bounds__(1024, 4) void k_gemm_f32(const u16* __restrict__ Wr,
                                                      const u16* __restrict__ ftr,
                                                      const void* __restrict__ offv,
                                                      const void* __restrict__ featv,
                                                      void* __restrict__ outv) {
  gemm_body(Wr, ftr, offv, featv, outv, 0);
}

__global__ __launch_bounds__(1024, 4) void k_gemm_bf16(const u16* __restrict__ Wr,
                                                       const u16* __restrict__ ftr,
                                                       const void* __restrict__ offv,
                                                       const void* __restrict__ featv,
                                                       void* __restrict__ outv) {
  gemm_body(Wr, ftr, offv, featv, outv, 1);
}

__global__ __launch_bounds__(1024, 4) void k_gemm_flag(const u16* __restrict__ Wr,
                                                       const u16* __restrict__ ftr,
                                                       const void* __restrict__ offv,
                                                       const void* __restrict__ featv,
                                                       void* __restrict__ outv,
                                                       const int* __restrict__ flag) {
  int isbf = *flag;
  asm volatile("s_waitcnt vmcnt(0)" ::: "memory");  // keep in-loop vmcnt exact
  gemm_body(Wr, ftr, offv, featv, outv, isbf);
}

extern "C" void kernel_launch(void* const* d_in, const int* in_sizes, int n_in,
                              void* d_out, int out_size, void* d_ws, size_t ws_size,
                              hipStream_t stream) {
  const void* feat = d_in[0];
  const void* offs = d_in[1];
  const void* wght = d_in[2];

  // workspace layout (256B-aligned sections)
  const size_t off_flag = 0;
  const size_t off_wr   = 256;                          // bf16 Wr, 1.125 MB
  const size_t off_ftr  = off_wr + (size_t)1179648;     // bf16 channels-last feature, 8 MB
  const size_t need     = off_ftr + (size_t)8388608;
  if (ws_size < need) return;  // insufficient scratch; cannot run

  char* ws = (char*)d_ws;
  int* flag = (int*)(ws + off_flag);
  u16* Wr   = (u16*)(ws + off_wr);
  u16* ftr  = (u16*)(ws + off_ftr);

  // Host-side dtype detection from input byte sizes (feature: 4*256*64*64
  // elems; f32 = 16777216 B, bf16 = 8388608 B), cross-checked vs weight
  // (256*256*9 elems; f32 = 2359296 B, bf16 = 1179648 B). Fallback to the
  // on-device probe only if sizes are ambiguous (e.g. element counts).
  int isbf_h = -1;
  if (in_sizes && n_in >= 3) {
    if (in_sizes[0] == 16777216 && in_sizes[2] == 2359296) isbf_h = 0;
    else if (in_sizes[0] == 8388608 && in_sizes[2] == 1179648) isbf_h = 1;
  }
  if (isbf_h < 0)
    k_detect<<<1, 256, 0, stream>>>((const u16*)feat, flag);
  k_prep<<<dim3(128, 8, 5), dim3(32, 8), 0, stream>>>(feat, ftr, wght, Wr, flag, isbf_h);
  if (isbf_h == 0)
    k_gemm_f32<<<J_TOT / 64, 1024, 0, stream>>>(Wr, ftr, offs, feat, d_out);
  else if (isbf_h == 1)
    k_gemm_bf16<<<J_TOT / 64, 1024, 0, stream>>>(Wr, ftr, offs, feat, d_out);
  else
    k_gemm_flag<<<J_TOT / 64, 1024, 0, stream>>>(Wr, ftr, offs, feat, d_out, flag);
}

// Round 13
// 129.792 us; speedup vs baseline: 1.3068x; 1.0059x over previous
//
#include <hip/hip_runtime.h>

// Problem constants: B=4, C=256, H=W=64, KS=3, N=9
#define HW    4096
#define J_TOT 16384   // B*H*W
#define K_TOT 2304    // 9*256
#define C_CH  256

typedef unsigned short u16;
typedef unsigned int   u32;
typedef __attribute__((ext_vector_type(8))) short short8;   // 8 bf16 (4 VGPRs), MFMA A/B frag
typedef __attribute__((ext_vector_type(4))) float f32x4;    // MFMA C/D frag
typedef __attribute__((ext_vector_type(4))) unsigned short us4;

__device__ __forceinline__ float b2f(u16 u) { return __uint_as_float(((u32)u) << 16); }
__device__ __forceinline__ u16 f2b(float x) {             // RNE f32->bf16
  u32 u = __float_as_uint(x);
  u += 0x7FFFu + ((u >> 16) & 1u);
  return (u16)(u >> 16);
}

// async global->LDS, 16B per lane; lds dst must be wave-uniform base (+lane*16 implicit)
__device__ __forceinline__ void gload_lds16(const u16* g, u16* l) {
  __builtin_amdgcn_global_load_lds(
      (__attribute__((address_space(1))) void*)(void*)g,
      (__attribute__((address_space(3))) void*)(void*)l, 16, 0, 0);
}

// ---------------------------------------------------------------------------
// Kernel 0 (FALLBACK ONLY -- launched only if out_size/in_sizes are both
// ambiguous): dtype detection (1 = bf16 inputs, 0 = f32 inputs).
// ---------------------------------------------------------------------------
__global__ void k_detect(const u16* __restrict__ f, int* __restrict__ flag) {
  __shared__ int sh[256];
  int t = threadIdx.x;
  int hits = 0;
  for (int i = t; i < 2048; i += 256) {
    u16 u = f[2 * i];
    int e = (u >> 7) & 0xFF;
    hits += (e >= 100 && e <= 141) ? 1 : 0;
  }
  sh[t] = hits;
  __syncthreads();
  if (t == 0) {
    int s = 0;
    for (int i = 0; i < 256; i++) s += sh[i];
    flag[0] = (s > 1024) ? 1 : 0;
  }
}

// ---------------------------------------------------------------------------
// Kernel 1 (merged prep): z<4 -> feature (b,c,h,w) -> channels-last bf16
// ftr[b][hw][c] (b = blockIdx.z); z==4 -> weight (o,c,3,3) -> Wr[o][k],
// k = n*256+c, via LDS so both global reads and writes are coalesced.
// ---------------------------------------------------------------------------
__global__ void k_prep(const void* __restrict__ featv, u16* __restrict__ ftr,
                       const void* __restrict__ wv, u16* __restrict__ Wr,
                       const int* __restrict__ flag, int isbf_h) {
  int isbf = (isbf_h >= 0) ? isbf_h : *flag;
  int tx = threadIdx.x;  // 0..31
  int ty = threadIdx.y;  // 0..7
  int z = blockIdx.z;
  if (z < 4) {
    __shared__ u16 tile[32][33];
    int b = z;
    int hw0 = blockIdx.x << 5;
    int c0 = blockIdx.y << 5;
    if (isbf) {
      const u16* f = (const u16*)featv;
#pragma unroll
      for (int i = 0; i < 4; i++) {
        int c = c0 + ty + i * 8;
        tile[ty + i * 8][tx] = f[(((size_t)(b * C_CH + c)) << 12) + hw0 + tx];
      }
    } else {
      const float* f = (const float*)featv;
#pragma unroll
      for (int i = 0; i < 4; i++) {
        int c = c0 + ty + i * 8;
        tile[ty + i * 8][tx] = f2b(f[(((size_t)(b * C_CH + c)) << 12) + hw0 + tx]);
      }
    }
    __syncthreads();
#pragma unroll
    for (int i = 0; i < 4; i++) {
      int hw = hw0 + ty + i * 8;
      ftr[(((size_t)(b * HW + hw)) << 8) + c0 + tx] = tile[tx][ty + i * 8];
    }
  } else {
    // weight repack: block = one output channel o; read o-slice (2304 elems,
    // contiguous, elem idx = c*9+n), LDS-transpose, write 9 contiguous
    // 256-elem segments (dst k = n*256+c).
    __shared__ u16 wtile[2304];
    int bid = blockIdx.x + (blockIdx.y << 7);   // 0..1023
    if (bid >= C_CH) return;
    int flat = ty * 32 + tx;                    // 0..255
    if (isbf) {
      const u16* wsrc = (const u16*)wv + (size_t)bid * K_TOT;
      for (int i = flat; i < K_TOT; i += 256) wtile[i] = wsrc[i];
    } else {
      const float* wsrc = (const float*)wv + (size_t)bid * K_TOT;
      for (int i = flat; i < K_TOT; i += 256) wtile[i] = f2b(wsrc[i]);
    }
    __syncthreads();
    u16* wdst = Wr + (size_t)bid * K_TOT;
#pragma unroll
    for (int n = 0; n < 9; n++) wdst[n * 256 + flat] = wtile[flat * 9 + n];
  }
}

// ---------------------------------------------------------------------------
// Kernel 2 (FUSED gather+GEMM): r12 body, byte-for-byte (measured 55.2us =
// best). isbf is a compile-time literal in the common path; r12's trace
// showed k_gemm_flag dispatched (in_sizes does NOT carry byte sizes), so
// this round adds out_size-based host detection (output = (4,256,64,64) in
// input dtype: 16777216 B = f32, 8388608 B = bf16) to actually hit the
// literal path and drop the k_detect launch.
//
// Structure (measured optimum, 12 rounds): block 64j x 256o, 1024 thr = 16
// waves (2j x 8o), wave tile 32jx32o, grid 256 = 1 block/CU = 4 waves/SIMD.
// XCD-chunked swizzle (FETCH 3x cut). A (Wr) via gload_lds16 DMA, triple-
// buffered (A-direct global->VGPR DEAD: r7/r9 +41us, per-XCD L2 channel
// saturation). B produced in LDS by bilinear interp (dup-1); np-cadenced
// table cache; counted barrier vmcnt(6)+lgkmcnt(0); swizzle slot cg^(p&7),
// reader g^(row&7): 0 conflicts measured.
// ---------------------------------------------------------------------------
#define NT 36   // K_TOT / 64

#define A_DMA(Ab)                                                            \
  do {                                                                       \
    gload_lds16(asrc0, (Ab) + wave * 1024);                                  \
    gload_lds16(asrc1, (Ab) + wave * 1024 + 512);                            \
    asrc0 += 64; asrc1 += 64;                                                \
  } while (0)

// load corner q-regs + snapshot weights for `tile` into slot P (a or b)
#define PLOAD_S(tile, P)                                                     \
  do {                                                                       \
    if (((tile) & 3) == 0) {                                                 \
      int np_ = (tile) >> 2;                                                 \
      tw0 = gs[np_][0][pp]; tw1 = gs[np_][1][pp];                            \
      tw2 = gs[np_][2][pp]; tw3 = gs[np_][3][pp];                            \
      ti0 = isx[np_][0][pp]; ti1 = isx[np_][1][pp];                          \
      ti2 = isx[np_][2][pp]; ti3 = isx[np_][3][pp];                          \
    }                                                                        \
    int c0_ = (((tile) & 3) << 6) + cb4;                                     \
    P##w0 = tw0; P##w1 = tw1; P##w2 = tw2; P##w3 = tw3;                      \
    P##q0 = *(const us4*)(ftr + ti0 + c0_);                                  \
    P##q1 = *(const us4*)(ftr + ti1 + c0_);                                  \
    P##q2 = *(const us4*)(ftr + ti2 + c0_);                                  \
    P##q3 = *(const us4*)(ftr + ti3 + c0_);                                  \
  } while (0)

#define PFIN_S(P, Bb)                                                        \
  do {                                                                       \
    us4 ov;                                                                  \
    _Pragma("unroll")                                                        \
    for (int i = 0; i < 4; i++) {                                            \
      float v = P##w0 * b2f(P##q0[i]) + P##w1 * b2f(P##q1[i]) +              \
                P##w2 * b2f(P##q2[i]) + P##w3 * b2f(P##q3[i]);               \
      ov[i] = f2b(v);                                                        \
    }                                                                        \
    *(us4*)((Bb) + bofs) = ov;                                               \
  } while (0)

#define GEMM_COMPUTE(Ab, Bb)                                                 \
  do {                                                                       \
    short8 af[2][2], bf[2][2];                                               \
    _Pragma("unroll")                                                        \
    for (int kk = 0; kk < 2; kk++) {                                         \
      int go = (((kk << 2) + lk) ^ swz) << 3;                                \
      _Pragma("unroll")                                                      \
      for (int oi = 0; oi < 2; oi++)                                         \
        af[oi][kk] = *(const short8*)((Ab) + (wo * 32 + oi * 16 + lr) * 64 + go); \
      _Pragma("unroll")                                                      \
      for (int ji = 0; ji < 2; ji++)                                         \
        bf[ji][kk] = *(const short8*)((Bb) + (wj * 32 + ji * 16 + lr) * 64 + go); \
    }                                                                        \
    __builtin_amdgcn_s_setprio(1);                                           \
    _Pragma("unroll")                                                        \
    for (int kk = 0; kk < 2; kk++)                                           \
      _Pragma("unroll")                                                      \
      for (int oi = 0; oi < 2; oi++)                                         \
        _Pragma("unroll")                                                    \
        for (int ji = 0; ji < 2; ji++)                                       \
          acc[oi][ji] = __builtin_amdgcn_mfma_f32_16x16x32_bf16(             \
              af[oi][kk], bf[ji][kk], acc[oi][ji], 0, 0, 0);                 \
    __builtin_amdgcn_s_setprio(0);                                           \
  } while (0)

#define CBAR()                                                               \
  do {                                                                       \
    asm volatile("s_waitcnt vmcnt(6) lgkmcnt(0)" ::: "memory");              \
    __builtin_amdgcn_s_barrier();                                            \
  } while (0)

#define ROTATE()                                                             \
  do {                                                                       \
    u16* tp_ = Ac; Ac = An; An = Af; Af = tp_;                               \
    tp_ = Bc; Bc = Bn; Bn = Bf; Bf = tp_;                                    \
  } while (0)

__device__ __forceinline__ void gemm_body(const u16* __restrict__ Wr,
                                          const u16* __restrict__ ftr,
                                          const void* __restrict__ offv,
                                          const void* __restrict__ featv,
                                          void* __restrict__ outv,
                                          const int isbf) {
  __shared__ u16 As[3][256 * 64];   // [o_row][k] 32KB x3
  __shared__ u16 Bs[3][64 * 64];    // [j_row][k]  8KB x3
  __shared__ float gs[9][4][64];    // bilinear weights, 9KB
  __shared__ int   isx[9][4][64];   // corner base offsets (elem, row<<8), 9KB
  // XCD-chunked bijective swizzle (nwg=256, 32 consecutive-j blocks per XCD)
  int bid = blockIdx.x;
  int xb = (bid & 7) * 32 + (bid >> 3);
  int j0 = xb << 6;
  int b = j0 >> 12;
  int hw0 = j0 & (HW - 1);
  int t = threadIdx.x;
  int wave = t >> 6, lane = t & 63;
  int wj = wave >> 3, wo = wave & 7;    // 2j x 8o wave grid
  int lr = lane & 15, lk = lane >> 4;
  int swz = lr & 7;

  // ---- phase 0: corner indices + weights for 64 pixels x 9 n (verified) ----
  if (t < 576) {
    int n = t >> 6, p = t & 63;
    int hw = hw0 + p;
    int h = hw >> 6, w = hw & 63;
    size_t obi = (((size_t)(b * 18 + n)) << 12) + hw;
    float ox, oy;
    if (isbf) {
      const u16* po = (const u16*)offv;
      ox = b2f(po[obi]);
      oy = b2f(po[obi + (9u << 12)]);
    } else {
      const float* po = (const float*)offv;
      ox = po[obi];
      oy = po[obi + (9u << 12)];
    }
    int ki = n / 3, kj = n % 3;
    float px = (float)(h + ki) + ox;
    float py = (float)(w + kj) + oy;
    float fx = floorf(px), fy = floorf(py);
    float qltx = fminf(fmaxf(fx, 0.f), 65.f);
    float qlty = fminf(fmaxf(fy, 0.f), 65.f);
    float qrbx = fminf(fmaxf(fx + 1.f, 0.f), 65.f);
    float qrby = fminf(fmaxf(fy + 1.f, 0.f), 65.f);
    float pcx = fminf(fmaxf(px, 0.f), 65.f);
    float pcy = fminf(fmaxf(py, 0.f), 65.f);
    float dltx = 1.f + (qltx - pcx);
    float drbx = 1.f - (qrbx - pcx);
    float dlty = 1.f + (qlty - pcy);
    float drby = 1.f - (qrby - pcy);
    float g0 = dltx * dlty;   // (q_lt_x, q_lt_y)
    float g1 = drbx * drby;   // (q_rb_x, q_rb_y)
    float g2 = dltx * drby;   // (q_lt_x, q_rb_y)
    float g3 = drbx * dlty;   // (q_rb_x, q_lt_y)
    int x0 = (int)qltx, y0 = (int)qlty, x1 = (int)qrbx, y1 = (int)qrby;
    int v0 = (x0 >= 1 && x0 <= 64 && y0 >= 1 && y0 <= 64);
    int v1 = (x1 >= 1 && x1 <= 64 && y1 >= 1 && y1 <= 64);
    int v2 = (x0 >= 1 && x0 <= 64 && y1 >= 1 && y1 <= 64);
    int v3 = (x1 >= 1 && x1 <= 64 && y0 >= 1 && y0 <= 64);
    int base = b << 12;
    isx[n][0][p] = v0 ? ((base + ((x0 - 1) << 6) + (y0 - 1)) << 8) : 0;
    isx[n][1][p] = v1 ? ((base + ((x1 - 1) << 6) + (y1 - 1)) << 8) : 0;
    isx[n][2][p] = v2 ? ((base + ((x0 - 1) << 6) + (y1 - 1)) << 8) : 0;
    isx[n][3][p] = v3 ? ((base + ((x1 - 1) << 6) + (y0 - 1)) << 8) : 0;
    gs[n][0][p] = v0 ? g0 : 0.f;
    gs[n][1][p] = v1 ? g1 : 0.f;
    gs[n][2][p] = v2 ? g2 : 0.f;
    gs[n][3][p] = v3 ? g3 : 0.f;
  }

  f32x4 acc[2][2];   // [oi][ji]
  f32x4 zero = {0.f, 0.f, 0.f, 0.f};
#pragma unroll
  for (int i = 0; i < 2; i++)
#pragma unroll
    for (int j = 0; j < 2; j++) acc[i][j] = zero;

  // A staging: wave w stages rows [16w,16w+16) of the 256 o-rows via 2
  // instrs; lane l covers row +(l>>3), source col-group pre-swizzled
  // (l&7)^(l>>3) so LDS slot (r,cg) holds global column (cg ^ (r&7)).
  int rb = lane >> 3;
  int cs = ((lane & 7) ^ rb) << 3;
  const u16* asrc0 = Wr + (size_t)(wave * 16 + 0 + rb) * K_TOT + cs;
  const u16* asrc1 = Wr + (size_t)(wave * 16 + 8 + rb) * K_TOT + cs;

  // B producer: thread (p = t>>4, q = t&15) owns 4 channels of pixel p:
  // channel-group cg = q>>1, half = q&1 -> channels cg*8+half*4 .. +4.
  int pp = t >> 4, qq = t & 15;
  int cgp = qq >> 1, half = qq & 1;
  int bofs = pp * 64 + ((cgp ^ (pp & 7)) << 3) + (half << 2);  // swizzled elem offset
  int cb4 = (cgp << 3) + (half << 2);                           // channel offset in 64-chunk

  u16 *Ac = &As[0][0], *An = &As[1][0], *Af = &As[2][0];
  u16 *Bc = &Bs[0][0], *Bn = &Bs[1][0], *Bf = &Bs[2][0];

  __syncthreads();   // phase-0 tables ready

  us4 aq0, aq1, aq2, aq3, bq0, bq1, bq2, bq3;
  float aw0, aw1, aw2, aw3, bw0, bw1, bw2, bw3;
  float tw0, tw1, tw2, tw3;
  int ti0, ti1, ti2, ti3;

  // prologue: tile0 -> cur (B produced immediately), tile1 -> nxt (A only;
  // B for tile1 produced in the first loop iteration). vmcnt(6) retires
  // exactly tile0's 6 VMEM (12 outstanding -> 6, in-order) before first use.
  PLOAD_S(0, a); A_DMA(Ac);
  PFIN_S(a, Bc);
  PLOAD_S(1, b); A_DMA(An);
  CBAR();

  // main loop: 34 sub-iters (tiles 0..33 computed), 2-unrolled for slot parity
#pragma unroll 1
  for (int it = 0; it < 17; ++it) {
    // even sub-iter: compute tile 2*it, produce B tile 2*it+1, prefetch 2*it+2
    PLOAD_S(2 * it + 2, a);
    A_DMA(Af);
    GEMM_COMPUTE(Ac, Bc);
    PFIN_S(b, Bn);
    CBAR();
    ROTATE();
    // odd sub-iter
    PLOAD_S(2 * it + 3, b);
    A_DMA(Af);
    GEMM_COMPUTE(Ac, Bc);
    PFIN_S(a, Bn);
    CBAR();
    ROTATE();
  }
  // epilogue: tiles 34, 35
  GEMM_COMPUTE(Ac, Bc);          // tile 34
  PFIN_S(b, Bn);                 // tile 35 B (slot b loaded at sub-iter tt=33)
  asm volatile("s_waitcnt vmcnt(0) lgkmcnt(0)" ::: "memory");
  __builtin_amdgcn_s_barrier();
  GEMM_COMPUTE(An, Bn);          // tile 35

  // epilogue: D mapping col = lane&15 (j), row = (lane>>4)*4 + r (o)
  int lq = lane >> 4;
#pragma unroll
  for (int oi = 0; oi < 2; oi++) {
#pragma unroll
    for (int ji = 0; ji < 2; ji++) {
      int j = j0 + wj * 32 + ji * 16 + lr;
      int bb_ = j >> 12, hw = j & (HW - 1);
      int o0 = wo * 32 + oi * 16 + lq * 4;
#pragma unroll
      for (int r = 0; r < 4; r++) {
        size_t oidx = (((size_t)(bb_ * C_CH + o0 + r)) << 12) + hw;
        float v = acc[oi][ji][r];
        v = fmaxf(v, 0.f);
        float ft = isbf ? b2f(((const u16*)featv)[oidx]) : ((const float*)featv)[oidx];
        v = fmaxf(v + ft, 0.f);
        if (isbf) ((u16*)outv)[oidx] = f2b(v);
        else      ((float*)outv)[oidx] = v;
      }
    }
  }
}

__global__ __launch_bounds__(1024, 4) void k_gemm_f32(const u16* __restrict__ Wr,
                                                      const u16* __restrict__ ftr,
                                                      const void* __restrict__ offv,
                                                      const void* __restrict__ featv,
                                                      void* __restrict__ outv) {
  gemm_body(Wr, ftr, offv, featv, outv, 0);
}

__global__ __launch_bounds__(1024, 4) void k_gemm_bf16(const u16* __restrict__ Wr,
                                                       const u16* __restrict__ ftr,
                                                       const void* __restrict__ offv,
                                                       const void* __restrict__ featv,
                                                       void* __restrict__ outv) {
  gemm_body(Wr, ftr, offv, featv, outv, 1);
}

__global__ __launch_bounds__(1024, 4) void k_gemm_flag(const u16* __restrict__ Wr,
                                                       const u16* __restrict__ ftr,
                                                       const void* __restrict__ offv,
                                                       const void* __restrict__ featv,
                                                       void* __restrict__ outv,
                                                       const int* __restrict__ flag) {
  int isbf = *flag;
  asm volatile("s_waitcnt vmcnt(0)" ::: "memory");  // keep in-loop vmcnt exact
  gemm_body(Wr, ftr, offv, featv, outv, isbf);
}

extern "C" void kernel_launch(void* const* d_in, const int* in_sizes, int n_in,
                              void* d_out, int out_size, void* d_ws, size_t ws_size,
                              hipStream_t stream) {
  const void* feat = d_in[0];
  const void* offs = d_in[1];
  const void* wght = d_in[2];

  // workspace layout (256B-aligned sections)
  const size_t off_flag = 0;
  const size_t off_wr   = 256;                          // bf16 Wr, 1.125 MB
  const size_t off_ftr  = off_wr + (size_t)1179648;     // bf16 channels-last feature, 8 MB
  const size_t need     = off_ftr + (size_t)8388608;
  if (ws_size < need) return;  // insufficient scratch; cannot run

  char* ws = (char*)d_ws;
  int* flag = (int*)(ws + off_flag);
  u16* Wr   = (u16*)(ws + off_wr);
  u16* ftr  = (u16*)(ws + off_ftr);

  // Host-side dtype detection, three tiers:
  //  1. out_size: output is (4,256,64,64) in the input dtype ->
  //     16777216 B = f32, 8388608 B = bf16.  (r12 trace proved in_sizes
  //     does NOT carry these byte values -- k_gemm_flag was dispatched.)
  //  2. in_sizes byte check (kept in case out_size is padded).
  //  3. on-device probe (k_detect) as last resort.
  int isbf_h = -1;
  if (out_size == 16777216) isbf_h = 0;
  else if (out_size == 8388608) isbf_h = 1;
  if (isbf_h < 0 && in_sizes && n_in >= 3) {
    if (in_sizes[0] == 16777216 && in_sizes[2] == 2359296) isbf_h = 0;
    else if (in_sizes[0] == 8388608 && in_sizes[2] == 1179648) isbf_h = 1;
  }
  if (isbf_h < 0)
    k_detect<<<1, 256, 0, stream>>>((const u16*)feat, flag);
  k_prep<<<dim3(128, 8, 5), dim3(32, 8), 0, stream>>>(feat, ftr, wght, Wr, flag, isbf_h);
  if (isbf_h == 0)
    k_gemm_f32<<<J_TOT / 64, 1024, 0, stream>>>(Wr, ftr, offs, feat, d_out);
  else if (isbf_h == 1)
    k_gemm_bf16<<<J_TOT / 64, 1024, 0, stream>>>(Wr, ftr, offs, feat, d_out);
  else
    k_gemm_flag<<<J_TOT / 64, 1024, 0, stream>>>(Wr, ftr, offs, feat, d_out, flag);
}